// Round 1
// baseline (840.150 us; speedup 1.0000x reference)
//
#include <hip/hip_runtime.h>
#include <hip/hip_bf16.h>
#include <stdint.h>

#define HID 2048
#define SEQ 4096
#define BATCH 2
#define NH 32
#define HD 64
#define ROWS (BATCH*SEQ)
#define LOCAL_H 30
#define LOG2E 1.4426950408889634f

typedef __attribute__((ext_vector_type(4))) float f32x4;
typedef __attribute__((ext_vector_type(8))) short s16x8;

__device__ __forceinline__ void g2l16(const void* g, void* l) {
  __builtin_amdgcn_global_load_lds((__attribute__((address_space(1))) void*)(g),
                                   (__attribute__((address_space(3))) void*)(l), 16, 0, 0);
}

// ---------------- cast f32 -> bf16, 8 elems/thread ----------------
__global__ __launch_bounds__(256) void castk(const float* __restrict__ s,
                                             __hip_bfloat16* __restrict__ d, int n8) {
  int i = blockIdx.x * 256 + threadIdx.x;
  if (i >= n8) return;
  const f32x4* sp = (const f32x4*)(s) + (size_t)i * 2;
  f32x4 a = sp[0], b = sp[1];
  __hip_bfloat16 t[8];
#pragma unroll
  for (int j = 0; j < 4; j++) { t[j] = __float2bfloat16(a[j]); t[j+4] = __float2bfloat16(b[j]); }
  *(s16x8*)(d + (size_t)i * 8) = *(const s16x8*)t;
}

// ---------------- NT GEMM: C[M][N] = A[M][K] * W[N][K]^T ----------------
// MODE 0: bf16 out row-major [row][HID]
// MODE 1: RoPE + 0.125 scale, scatter to Q[b][h][l][d]
// MODE 2: RoPE, scatter to K[b][h][l][d]
// MODE 3: f32 out + bias (final projection)
template<int MODE>
__global__ __launch_bounds__(256) void gemm_nt(const __hip_bfloat16* __restrict__ A,
                                               const __hip_bfloat16* __restrict__ W,
                                               const float* __restrict__ bias,
                                               void* __restrict__ outp, int M, int K) {
  __shared__ __hip_bfloat16 As[128 * 64];
  __shared__ __hip_bfloat16 Bs[128 * 64];
  const int tid = threadIdx.x;
  const int lane = tid & 63, wv = tid >> 6;
  const int wr = wv >> 1, wc = wv & 1;
  const int g = lane >> 4, ln = lane & 15;
  const int m0 = blockIdx.y * 128, n0 = blockIdx.x * 128;

  f32x4 acc[4][4];
#pragma unroll
  for (int i = 0; i < 4; i++)
#pragma unroll
    for (int j = 0; j < 4; j++) acc[i][j] = (f32x4)0.f;

  for (int kt = 0; kt < K; kt += 64) {
    __syncthreads();
    // stage A tile: 128 rows x 64 cols bf16 = 16KB = 1024 x 16B chunks
#pragma unroll
    for (int i = 0; i < 4; i++) {
      int c = i * 256 + tid;
      int row = c >> 3, slot = c & 7;
      int colE = ((slot ^ (row & 7)) * 8);       // pre-swizzled source (XOR on 16B slot)
      g2l16(A + (size_t)(m0 + row) * K + kt + colE,
            (void*)(As + (i * 256 + wv * 64) * 8));
    }
#pragma unroll
    for (int i = 0; i < 4; i++) {
      int c = i * 256 + tid;
      int row = c >> 3, slot = c & 7;
      int colE = ((slot ^ (row & 7)) * 8);
      g2l16(W + (size_t)(n0 + row) * K + kt + colE,
            (void*)(Bs + (i * 256 + wv * 64) * 8));
    }
    __syncthreads();
#pragma unroll
    for (int ks = 0; ks < 2; ks++) {
      s16x8 af[4], bfr[4];
#pragma unroll
      for (int i = 0; i < 4; i++) {
        int row = wr * 64 + i * 16 + ln;
        af[i] = *(const s16x8*)(As + row * 64 + (((ks * 4 + g) ^ (row & 7)) * 8));
      }
#pragma unroll
      for (int j = 0; j < 4; j++) {
        int row = wc * 64 + j * 16 + ln;
        bfr[j] = *(const s16x8*)(Bs + row * 64 + (((ks * 4 + g) ^ (row & 7)) * 8));
      }
#pragma unroll
      for (int i = 0; i < 4; i++)
#pragma unroll
        for (int j = 0; j < 4; j++)
          acc[i][j] = __builtin_amdgcn_mfma_f32_16x16x32_bf16(af[i], bfr[j], acc[i][j], 0, 0, 0);
    }
  }

  // epilogue: D layout col = lane&15, row = (lane>>4)*4 + r  [m89 verified]
#pragma unroll
  for (int i = 0; i < 4; i++) {
#pragma unroll
    for (int r = 0; r < 4; r++) {
      int grow = m0 + wr * 64 + i * 16 + g * 4 + r;
      if constexpr (MODE == 0) {
        __hip_bfloat16* o = (__hip_bfloat16*)outp + (size_t)grow * HID + n0 + wc * 64;
#pragma unroll
        for (int j = 0; j < 4; j++) o[j * 16 + ln] = __float2bfloat16(acc[i][j][r]);
      } else if constexpr (MODE == 3) {
        float* o = (float*)outp + (size_t)grow * HID + n0 + wc * 64;
#pragma unroll
        for (int j = 0; j < 4; j++)
          o[j * 16 + ln] = acc[i][j][r] + bias[n0 + wc * 64 + j * 16 + ln];
      } else {
        int b = grow >> 12, l = grow & (SEQ - 1);
        int h = (n0 >> 6) + wc;   // wave's 64 cols = one head
        __hip_bfloat16* o = (__hip_bfloat16*)outp + ((size_t)(b * NH + h) * SEQ + l) * HD;
#pragma unroll
        for (int j = 0; j < 2; j++) {
          int d = j * 16 + ln;                       // d < 32; partner d+32 = cols (j+2)
          float x1 = acc[i][j][r], x2 = acc[i][j + 2][r];
          // inv_freq = 10000^(-d/32) = 2^(-d*log2(10000)/32)
          float ang = (float)l * exp2f((float)d * -0.41524101186091903f);
          float sn, cs;
          sincosf(ang, &sn, &cs);
          float o1 = x1 * cs - x2 * sn;
          float o2 = x2 * cs + x1 * sn;
          if constexpr (MODE == 1) { o1 *= 0.125f; o2 *= 0.125f; }
          o[d]      = __float2bfloat16(o1);
          o[d + 32] = __float2bfloat16(o2);
        }
      }
    }
  }
}

// ---------------- V transpose: vlin[b*SEQ+l][h*64+d] -> Vt[(b*32+h)*64+d][SEQ] ----------------
__global__ __launch_bounds__(256) void transpose_v(const __hip_bfloat16* __restrict__ vlin,
                                                   __hip_bfloat16* __restrict__ vt) {
  __shared__ __hip_bfloat16 T[64][72];
  int blk = blockIdx.x;
  int l0 = (blk & 63) * 64;
  int bh = blk >> 6;
  int tid = threadIdx.x;
  {
    int l = tid >> 2, dq = (tid & 3) * 16;
    const __hip_bfloat16* src = vlin + (size_t)((bh >> 5) * SEQ + l0 + l) * HID + (bh & 31) * HD + dq;
    s16x8 v0 = *(const s16x8*)(src);
    s16x8 v1 = *(const s16x8*)(src + 8);
    *(s16x8*)&T[l][dq] = v0;
    *(s16x8*)&T[l][dq + 8] = v1;
  }
  __syncthreads();
  {
    int d = tid >> 2, lq = (tid & 3) * 16;
    __hip_bfloat16 tmp[16];
#pragma unroll
    for (int e = 0; e < 16; e++) tmp[e] = T[lq + e][d];
    __hip_bfloat16* dst = vt + ((size_t)bh * HD + d) * SEQ + l0 + lq;
    *(s16x8*)dst = *(const s16x8*)tmp;
    *(s16x8*)(dst + 8) = *(const s16x8*)(tmp + 8);
  }
}

// ---------------- flash attention (local sliding-window + global causal) ----------------
// Q pre-scaled by 0.125. Q,K: [bh][l][64]; Vt: [bh][64][SEQ]; out attn: [b*SEQ+l][HID] bf16
__global__ __launch_bounds__(256) void flash(const __hip_bfloat16* __restrict__ Q,
                                             const __hip_bfloat16* __restrict__ Kk,
                                             const __hip_bfloat16* __restrict__ Vt,
                                             __hip_bfloat16* __restrict__ attn) {
  __shared__ __hip_bfloat16 Ks[64 * 64];
  __shared__ __hip_bfloat16 Vs[64 * 64];
  __shared__ __hip_bfloat16 Pls[4][16 * 72];

  int qt = blockIdx.x & 63;
  int bh = blockIdx.x >> 6;
  int h = bh & 31;
  int q0 = qt * 64;
  int tid = threadIdx.x, lane = tid & 63, wv = tid >> 6;
  int g = lane >> 4, ln = lane & 15;

  int ks0;
  if (h < LOCAL_H) { int qb = q0 >> 10; ks0 = qb * 1024 - 512; if (ks0 < 0) ks0 = 0; }
  else ks0 = 0;
  int kend = q0 + 64;

  // Q fragments (rows q0 + wv*16 + ln)
  int qrow = q0 + wv * 16 + ln;
  const __hip_bfloat16* qbase = Q + ((size_t)bh * SEQ + qrow) * HD + g * 8;
  s16x8 qf0 = *(const s16x8*)(qbase);
  s16x8 qf1 = *(const s16x8*)(qbase + 32);

  float mrow[4], lrow[4];
  f32x4 o[4];
#pragma unroll
  for (int r = 0; r < 4; r++) { mrow[r] = -3.0e38f; lrow[r] = 0.f; }
#pragma unroll
  for (int dt = 0; dt < 4; dt++) o[dt] = (f32x4)0.f;

  for (int kc = ks0; kc < kend; kc += 64) {
    __syncthreads();
    // stage K chunk (64x64, XOR-swizzled via pre-swizzled global source)
#pragma unroll
    for (int i = 0; i < 2; i++) {
      int c = i * 256 + tid;
      int row = c >> 3, slot = c & 7;
      int colE = ((slot ^ (row & 7)) * 8);
      g2l16(Kk + ((size_t)bh * SEQ + kc + row) * HD + colE,
            (void*)(Ks + (i * 256 + wv * 64) * 8));
    }
    // stage V^T chunk: Vs[d][k]
#pragma unroll
    for (int i = 0; i < 2; i++) {
      int c = i * 256 + tid;
      int row = c >> 3, slot = c & 7;     // row = d
      int colE = ((slot ^ (row & 7)) * 8);
      g2l16(Vt + ((size_t)bh * HD + row) * SEQ + kc + colE,
            (void*)(Vs + (i * 256 + wv * 64) * 8));
    }
    __syncthreads();

    // S = Q K^T
    f32x4 s[4];
#pragma unroll
    for (int kt = 0; kt < 4; kt++) s[kt] = (f32x4)0.f;
#pragma unroll
    for (int kt = 0; kt < 4; kt++) {
      int row = kt * 16 + ln;
      int sw = row & 7;
      s16x8 kf0 = *(const s16x8*)(Ks + row * 64 + ((g ^ sw) * 8));
      s16x8 kf1 = *(const s16x8*)(Ks + row * 64 + (((4 + g) ^ sw) * 8));
      s[kt] = __builtin_amdgcn_mfma_f32_16x16x32_bf16(qf0, kf0, s[kt], 0, 0, 0);
      s[kt] = __builtin_amdgcn_mfma_f32_16x16x32_bf16(qf1, kf1, s[kt], 0, 0, 0);
    }

    if (kc == q0) {           // diagonal chunk: causal mask (key > q)
      int qq = wv * 16 + g * 4;
#pragma unroll
      for (int kt = 0; kt < 4; kt++) {
        int key = kt * 16 + ln;
#pragma unroll
        for (int r = 0; r < 4; r++)
          if (key > qq + r) s[kt][r] = -3.0e38f;
      }
    }

    // online softmax (row = q0 + wv*16 + g*4 + r, spread over 16 lanes)
#pragma unroll
    for (int r = 0; r < 4; r++) {
      float mc = fmaxf(fmaxf(s[0][r], s[1][r]), fmaxf(s[2][r], s[3][r]));
      mc = fmaxf(mc, __shfl_xor(mc, 1));
      mc = fmaxf(mc, __shfl_xor(mc, 2));
      mc = fmaxf(mc, __shfl_xor(mc, 4));
      mc = fmaxf(mc, __shfl_xor(mc, 8));
      float mnew = fmaxf(mrow[r], mc);
      float corr = exp2f((mrow[r] - mnew) * LOG2E);
      float psum = 0.f;
#pragma unroll
      for (int kt = 0; kt < 4; kt++) {
        float p = exp2f((s[kt][r] - mnew) * LOG2E);
        s[kt][r] = p;
        psum += p;
      }
      psum += __shfl_xor(psum, 1);
      psum += __shfl_xor(psum, 2);
      psum += __shfl_xor(psum, 4);
      psum += __shfl_xor(psum, 8);
      lrow[r] = lrow[r] * corr + psum;
      mrow[r] = mnew;
#pragma unroll
      for (int dt = 0; dt < 4; dt++) o[dt][r] *= corr;
    }

    // write P (bf16) to per-wave LDS region [16 rows][72]
    __hip_bfloat16* pw = &Pls[wv][0];
#pragma unroll
    for (int kt = 0; kt < 4; kt++)
#pragma unroll
      for (int r = 0; r < 4; r++)
        pw[(g * 4 + r) * 72 + kt * 16 + ln] = __float2bfloat16(s[kt][r]);

    // P fragments (A-operand: row = ln, k-slice = ks2*32 + g*8)
    s16x8 pf0 = *(const s16x8*)(pw + ln * 72 + g * 8);
    s16x8 pf1 = *(const s16x8*)(pw + ln * 72 + 32 + g * 8);

    // O += P * V
#pragma unroll
    for (int dt = 0; dt < 4; dt++) {
      int row = dt * 16 + ln;
      int sw = row & 7;
      s16x8 vf0 = *(const s16x8*)(Vs + row * 64 + ((g ^ sw) * 8));
      s16x8 vf1 = *(const s16x8*)(Vs + row * 64 + (((4 + g) ^ sw) * 8));
      o[dt] = __builtin_amdgcn_mfma_f32_16x16x32_bf16(pf0, vf0, o[dt], 0, 0, 0);
      o[dt] = __builtin_amdgcn_mfma_f32_16x16x32_bf16(pf1, vf1, o[dt], 0, 0, 0);
    }
  }

  // epilogue: normalize and write attn [row][h*64+d]
#pragma unroll
  for (int r = 0; r < 4; r++) {
    float linv = 1.0f / lrow[r];
    int grow = (bh >> 5) * SEQ + q0 + wv * 16 + g * 4 + r;
    __hip_bfloat16* od = attn + (size_t)grow * HID + h * HD;
#pragma unroll
    for (int dt = 0; dt < 4; dt++)
      od[dt * 16 + ln] = __float2bfloat16(o[dt][r] * linv);
  }
}

extern "C" void kernel_launch(void* const* d_in, const int* in_sizes, int n_in,
                              void* d_out, int out_size, void* d_ws, size_t ws_size,
                              hipStream_t stream) {
  (void)in_sizes; (void)n_in; (void)out_size; (void)ws_size;
  const float* hid = (const float*)d_in[0];
  const float* Wq  = (const float*)d_in[1];
  const float* Wk  = (const float*)d_in[2];
  const float* Wv  = (const float*)d_in[3];
  const float* Wo  = (const float*)d_in[4];
  const float* bo  = (const float*)d_in[5];

  char* ws = (char*)d_ws;
  size_t off = 0;
  __hip_bfloat16* hidB = (__hip_bfloat16*)(ws + off); off += (size_t)ROWS * HID * 2;  // 33.5MB
  __hip_bfloat16* WqB  = (__hip_bfloat16*)(ws + off); off += (size_t)HID * HID * 2;
  __hip_bfloat16* WkB  = (__hip_bfloat16*)(ws + off); off += (size_t)HID * HID * 2;
  __hip_bfloat16* WvB  = (__hip_bfloat16*)(ws + off); off += (size_t)HID * HID * 2;
  __hip_bfloat16* WoB  = (__hip_bfloat16*)(ws + off); off += (size_t)HID * HID * 2;
  __hip_bfloat16* Qr   = (__hip_bfloat16*)(ws + off); off += (size_t)ROWS * HID * 2;
  __hip_bfloat16* Kr   = (__hip_bfloat16*)(ws + off); off += (size_t)ROWS * HID * 2;
  __hip_bfloat16* vlin = (__hip_bfloat16*)(ws + off); off += (size_t)ROWS * HID * 2;
  __hip_bfloat16* Vt   = hidB;       // alias: hidden bf16 dead after QKV GEMMs
  __hip_bfloat16* attn = vlin;       // alias: vlin dead after transpose_v

  // casts
  castk<<<(ROWS * HID / 8 + 255) / 256, 256, 0, stream>>>(hid, hidB, ROWS * HID / 8);
  castk<<<(HID * HID / 8 + 255) / 256, 256, 0, stream>>>(Wq, WqB, HID * HID / 8);
  castk<<<(HID * HID / 8 + 255) / 256, 256, 0, stream>>>(Wk, WkB, HID * HID / 8);
  castk<<<(HID * HID / 8 + 255) / 256, 256, 0, stream>>>(Wv, WvB, HID * HID / 8);
  castk<<<(HID * HID / 8 + 255) / 256, 256, 0, stream>>>(Wo, WoB, HID * HID / 8);

  dim3 gg(HID / 128, ROWS / 128);   // 16 x 64
  gemm_nt<1><<<gg, 256, 0, stream>>>(hidB, WqB, nullptr, (void*)Qr, ROWS, HID);
  gemm_nt<2><<<gg, 256, 0, stream>>>(hidB, WkB, nullptr, (void*)Kr, ROWS, HID);
  gemm_nt<0><<<gg, 256, 0, stream>>>(hidB, WvB, nullptr, (void*)vlin, ROWS, HID);

  transpose_v<<<BATCH * NH * (SEQ / 64), 256, 0, stream>>>(vlin, Vt);

  flash<<<BATCH * NH * (SEQ / 64), 256, 0, stream>>>(Qr, Kr, Vt, attn);

  gemm_nt<3><<<gg, 256, 0, stream>>>(attn, WoB, bo, d_out, ROWS, HID);
}

// Round 2
// 809.479 us; speedup vs baseline: 1.0379x; 1.0379x over previous
//
#include <hip/hip_runtime.h>
#include <hip/hip_bf16.h>
#include <stdint.h>

#define HID 2048
#define SEQ 4096
#define BATCH 2
#define NH 32
#define HD 64
#define ROWS (BATCH*SEQ)
#define LOCAL_H 30
#define LOG2E 1.4426950408889634f

typedef __attribute__((ext_vector_type(4))) float f32x4;
typedef __attribute__((ext_vector_type(8))) short s16x8;

__device__ __forceinline__ void g2l16(const void* g, void* l) {
  __builtin_amdgcn_global_load_lds((__attribute__((address_space(1))) void*)(g),
                                   (__attribute__((address_space(3))) void*)(l), 16, 0, 0);
}

// ---------------- cast f32 -> bf16, 8 elems/thread ----------------
__global__ __launch_bounds__(256) void castk(const float* __restrict__ s,
                                             __hip_bfloat16* __restrict__ d, int n8) {
  int i = blockIdx.x * 256 + threadIdx.x;
  if (i >= n8) return;
  const f32x4* sp = (const f32x4*)(s) + (size_t)i * 2;
  f32x4 a = sp[0], b = sp[1];
  __hip_bfloat16 t[8];
#pragma unroll
  for (int j = 0; j < 4; j++) { t[j] = __float2bfloat16(a[j]); t[j+4] = __float2bfloat16(b[j]); }
  *(s16x8*)(d + (size_t)i * 8) = *(const s16x8*)t;
}

// ---------------- NT GEMM: C[M][N] = A[M][K] * W[N][K]^T ----------------
// MODE 0: bf16 out row-major [row][HID]
// MODE 1: RoPE + 0.125*log2e scale (Q in log2 domain), scatter to Q[b][h][l][d]
// MODE 2: RoPE, scatter to K[b][h][l][d]
// MODE 3: f32 out + bias (final projection)
template<int MODE>
__global__ __launch_bounds__(256) void gemm_nt(const __hip_bfloat16* __restrict__ A,
                                               const __hip_bfloat16* __restrict__ W,
                                               const float* __restrict__ bias,
                                               void* __restrict__ outp, int M, int K) {
  __shared__ __hip_bfloat16 As[128 * 64];
  __shared__ __hip_bfloat16 Bs[128 * 64];
  const int tid = threadIdx.x;
  const int lane = tid & 63, wv = tid >> 6;
  const int wr = wv >> 1, wc = wv & 1;
  const int g = lane >> 4, ln = lane & 15;
  const int m0 = blockIdx.y * 128, n0 = blockIdx.x * 128;

  f32x4 acc[4][4];
#pragma unroll
  for (int i = 0; i < 4; i++)
#pragma unroll
    for (int j = 0; j < 4; j++) acc[i][j] = (f32x4)0.f;

  for (int kt = 0; kt < K; kt += 64) {
    __syncthreads();
#pragma unroll
    for (int i = 0; i < 4; i++) {
      int c = i * 256 + tid;
      int row = c >> 3, slot = c & 7;
      int colE = ((slot ^ (row & 7)) * 8);
      g2l16(A + (size_t)(m0 + row) * K + kt + colE,
            (void*)(As + (i * 256 + wv * 64) * 8));
    }
#pragma unroll
    for (int i = 0; i < 4; i++) {
      int c = i * 256 + tid;
      int row = c >> 3, slot = c & 7;
      int colE = ((slot ^ (row & 7)) * 8);
      g2l16(W + (size_t)(n0 + row) * K + kt + colE,
            (void*)(Bs + (i * 256 + wv * 64) * 8));
    }
    __syncthreads();
#pragma unroll
    for (int ks = 0; ks < 2; ks++) {
      s16x8 af[4], bfr[4];
#pragma unroll
      for (int i = 0; i < 4; i++) {
        int row = wr * 64 + i * 16 + ln;
        af[i] = *(const s16x8*)(As + row * 64 + (((ks * 4 + g) ^ (row & 7)) * 8));
      }
#pragma unroll
      for (int j = 0; j < 4; j++) {
        int row = wc * 64 + j * 16 + ln;
        bfr[j] = *(const s16x8*)(Bs + row * 64 + (((ks * 4 + g) ^ (row & 7)) * 8));
      }
#pragma unroll
      for (int i = 0; i < 4; i++)
#pragma unroll
        for (int j = 0; j < 4; j++)
          acc[i][j] = __builtin_amdgcn_mfma_f32_16x16x32_bf16(af[i], bfr[j], acc[i][j], 0, 0, 0);
    }
  }

#pragma unroll
  for (int i = 0; i < 4; i++) {
#pragma unroll
    for (int r = 0; r < 4; r++) {
      int grow = m0 + wr * 64 + i * 16 + g * 4 + r;
      if constexpr (MODE == 0) {
        __hip_bfloat16* o = (__hip_bfloat16*)outp + (size_t)grow * HID + n0 + wc * 64;
#pragma unroll
        for (int j = 0; j < 4; j++) o[j * 16 + ln] = __float2bfloat16(acc[i][j][r]);
      } else if constexpr (MODE == 3) {
        float* o = (float*)outp + (size_t)grow * HID + n0 + wc * 64;
#pragma unroll
        for (int j = 0; j < 4; j++)
          o[j * 16 + ln] = acc[i][j][r] + bias[n0 + wc * 64 + j * 16 + ln];
      } else {
        int b = grow >> 12, l = grow & (SEQ - 1);
        int h = (n0 >> 6) + wc;
        __hip_bfloat16* o = (__hip_bfloat16*)outp + ((size_t)(b * NH + h) * SEQ + l) * HD;
#pragma unroll
        for (int j = 0; j < 2; j++) {
          int d = j * 16 + ln;
          float x1 = acc[i][j][r], x2 = acc[i][j + 2][r];
          float ang = (float)l * exp2f((float)d * -0.41524101186091903f);
          float sn, cs;
          sincosf(ang, &sn, &cs);
          float o1 = x1 * cs - x2 * sn;
          float o2 = x2 * cs + x1 * sn;
          if constexpr (MODE == 1) { o1 *= 0.125f * LOG2E; o2 *= 0.125f * LOG2E; }
          o[d]      = __float2bfloat16(o1);
          o[d + 32] = __float2bfloat16(o2);
        }
      }
    }
  }
}

// ---------------- V transpose ----------------
__global__ __launch_bounds__(256) void transpose_v(const __hip_bfloat16* __restrict__ vlin,
                                                   __hip_bfloat16* __restrict__ vt) {
  __shared__ __hip_bfloat16 T[64][72];
  int blk = blockIdx.x;
  int l0 = (blk & 63) * 64;
  int bh = blk >> 6;
  int tid = threadIdx.x;
  {
    int l = tid >> 2, dq = (tid & 3) * 16;
    const __hip_bfloat16* src = vlin + (size_t)((bh >> 5) * SEQ + l0 + l) * HID + (bh & 31) * HD + dq;
    s16x8 v0 = *(const s16x8*)(src);
    s16x8 v1 = *(const s16x8*)(src + 8);
    *(s16x8*)&T[l][dq] = v0;
    *(s16x8*)&T[l][dq + 8] = v1;
  }
  __syncthreads();
  {
    int d = tid >> 2, lq = (tid & 3) * 16;
    __hip_bfloat16 tmp[16];
#pragma unroll
    for (int e = 0; e < 16; e++) tmp[e] = T[lq + e][d];
    __hip_bfloat16* dst = vt + ((size_t)bh * HD + d) * SEQ + l0 + lq;
    *(s16x8*)dst = *(const s16x8*)tmp;
    *(s16x8*)(dst + 8) = *(const s16x8*)(tmp + 8);
  }
}

// ---------------- flash attention: QBLK=128, 8 waves, double-buffered, XCD-grouped ----------------
// Q pre-scaled by 0.125*log2e (log2 domain). Q,K: [bh][l][64]; Vt: [bh][64][SEQ]
__global__ __launch_bounds__(512) void flash(const __hip_bfloat16* __restrict__ Q,
                                             const __hip_bfloat16* __restrict__ Kk,
                                             const __hip_bfloat16* __restrict__ Vt,
                                             __hip_bfloat16* __restrict__ attn) {
  __shared__ __hip_bfloat16 Ks[2][64 * 64];
  __shared__ __hip_bfloat16 Vs[2][64 * 64];
  __shared__ __hip_bfloat16 Pls[8][16 * 72];

  // XCD-grouping swizzle: all 32 q-tiles of a head land on one XCD (2048 blocks, 8 XCDs)
  int blk = blockIdx.x;
  int gw = (blk & 7) * 256 + (blk >> 3);
  int qt = gw & 31;
  int bh = gw >> 5;
  int h = bh & 31;
  int q0 = qt * 128;
  int tid = threadIdx.x, lane = tid & 63, wv = tid >> 6;
  int g = lane >> 4, ln = lane & 15;

  int ks0 = 0;
  if (h < LOCAL_H) { ks0 = (q0 >> 10) * 1024 - 512; if (ks0 < 0) ks0 = 0; }
  int kend = q0 + 128;
  int nch = (kend - ks0) >> 6;

  // Q fragments (rows q0 + wv*16 + ln)
  int qrow = q0 + wv * 16 + ln;
  const __hip_bfloat16* qbase = Q + ((size_t)bh * SEQ + qrow) * HD + g * 8;
  s16x8 qf0 = *(const s16x8*)(qbase);
  s16x8 qf1 = *(const s16x8*)(qbase + 32);

  float mrow[4], lrow[4];
  f32x4 o[4];
#pragma unroll
  for (int r = 0; r < 4; r++) { mrow[r] = -3.0e38f; lrow[r] = 0.f; }
#pragma unroll
  for (int dt = 0; dt < 4; dt++) o[dt] = (f32x4)0.f;

  // staging: 512 threads, 1 K-load + 1 V-load each per chunk
  const int srow = tid >> 3, sslot = tid & 7;
  const int scolE = (sslot ^ (srow & 7)) * 8;

  // prologue: stage chunk 0 into buffer 0
  {
    int kc = ks0;
    g2l16(Kk + ((size_t)bh * SEQ + kc + srow) * HD + scolE, (void*)(&Ks[0][0] + wv * 512));
    g2l16(Vt + ((size_t)bh * HD + srow) * SEQ + kc + scolE, (void*)(&Vs[0][0] + wv * 512));
  }

  int cur = 0;
  for (int ci = 0; ci < nch; ci++) {
    int kc = ks0 + ci * 64;
    if (ci + 1 < nch) {
      int kn = kc + 64;
      g2l16(Kk + ((size_t)bh * SEQ + kn + srow) * HD + scolE, (void*)(&Ks[cur ^ 1][0] + wv * 512));
      g2l16(Vt + ((size_t)bh * HD + srow) * SEQ + kn + scolE, (void*)(&Vs[cur ^ 1][0] + wv * 512));
      asm volatile("s_waitcnt vmcnt(2)" ::: "memory");
    } else {
      asm volatile("s_waitcnt vmcnt(0)" ::: "memory");
    }
    __builtin_amdgcn_s_barrier();
    __builtin_amdgcn_sched_barrier(0);

    if (kc <= q0 + wv * 16 + 15) {   // wave-uniform: skip fully-masked chunks
      const __hip_bfloat16* Kc = &Ks[cur][0];
      const __hip_bfloat16* Vc = &Vs[cur][0];

      f32x4 s[4];
#pragma unroll
      for (int kt = 0; kt < 4; kt++) s[kt] = (f32x4)0.f;
#pragma unroll
      for (int kt = 0; kt < 4; kt++) {
        int row = kt * 16 + ln;
        int sw = row & 7;
        s16x8 kf0 = *(const s16x8*)(Kc + row * 64 + ((g ^ sw) * 8));
        s16x8 kf1 = *(const s16x8*)(Kc + row * 64 + (((4 + g) ^ sw) * 8));
        s[kt] = __builtin_amdgcn_mfma_f32_16x16x32_bf16(qf0, kf0, s[kt], 0, 0, 0);
        s[kt] = __builtin_amdgcn_mfma_f32_16x16x32_bf16(qf1, kf1, s[kt], 0, 0, 0);
      }

      if (kc + 63 > q0 + wv * 16) {  // diagonal region: causal mask (key > q)
        int qq = (q0 - kc) + wv * 16 + g * 4;
#pragma unroll
        for (int kt = 0; kt < 4; kt++) {
          int key = kt * 16 + ln;
#pragma unroll
          for (int r = 0; r < 4; r++)
            if (key > qq + r) s[kt][r] = -1.0e30f;
        }
      }

      // online softmax in log2 domain
#pragma unroll
      for (int r = 0; r < 4; r++) {
        float mc = fmaxf(fmaxf(s[0][r], s[1][r]), fmaxf(s[2][r], s[3][r]));
        mc = fmaxf(mc, __shfl_xor(mc, 1));
        mc = fmaxf(mc, __shfl_xor(mc, 2));
        mc = fmaxf(mc, __shfl_xor(mc, 4));
        mc = fmaxf(mc, __shfl_xor(mc, 8));
        float mnew = fmaxf(mrow[r], mc);
        float corr = exp2f(mrow[r] - mnew);
        float psum = 0.f;
#pragma unroll
        for (int kt = 0; kt < 4; kt++) {
          float p = exp2f(s[kt][r] - mnew);
          s[kt][r] = p;
          psum += p;
        }
        psum += __shfl_xor(psum, 1);
        psum += __shfl_xor(psum, 2);
        psum += __shfl_xor(psum, 4);
        psum += __shfl_xor(psum, 8);
        lrow[r] = lrow[r] * corr + psum;
        mrow[r] = mnew;
#pragma unroll
        for (int dt = 0; dt < 4; dt++) o[dt][r] *= corr;
      }

      // P -> per-wave LDS, read back as A-fragments
      __hip_bfloat16* pw = &Pls[wv][0];
#pragma unroll
      for (int kt = 0; kt < 4; kt++)
#pragma unroll
        for (int r = 0; r < 4; r++)
          pw[(g * 4 + r) * 72 + kt * 16 + ln] = __float2bfloat16(s[kt][r]);

      s16x8 pf0 = *(const s16x8*)(pw + ln * 72 + g * 8);
      s16x8 pf1 = *(const s16x8*)(pw + ln * 72 + 32 + g * 8);

#pragma unroll
      for (int dt = 0; dt < 4; dt++) {
        int row = dt * 16 + ln;
        int sw = row & 7;
        s16x8 vf0 = *(const s16x8*)(Vc + row * 64 + ((g ^ sw) * 8));
        s16x8 vf1 = *(const s16x8*)(Vc + row * 64 + (((4 + g) ^ sw) * 8));
        o[dt] = __builtin_amdgcn_mfma_f32_16x16x32_bf16(pf0, vf0, o[dt], 0, 0, 0);
        o[dt] = __builtin_amdgcn_mfma_f32_16x16x32_bf16(pf1, vf1, o[dt], 0, 0, 0);
      }
    }

    __builtin_amdgcn_sched_barrier(0);
    asm volatile("s_waitcnt lgkmcnt(0)" ::: "memory");
    __builtin_amdgcn_s_barrier();
    cur ^= 1;
  }

#pragma unroll
  for (int r = 0; r < 4; r++) {
    float linv = 1.0f / lrow[r];
    int grow = (bh >> 5) * SEQ + q0 + wv * 16 + g * 4 + r;
    __hip_bfloat16* od = attn + (size_t)grow * HID + h * HD;
#pragma unroll
    for (int dt = 0; dt < 4; dt++)
      od[dt * 16 + ln] = __float2bfloat16(o[dt][r] * linv);
  }
}

extern "C" void kernel_launch(void* const* d_in, const int* in_sizes, int n_in,
                              void* d_out, int out_size, void* d_ws, size_t ws_size,
                              hipStream_t stream) {
  (void)in_sizes; (void)n_in; (void)out_size; (void)ws_size;
  const float* hid = (const float*)d_in[0];
  const float* Wq  = (const float*)d_in[1];
  const float* Wk  = (const float*)d_in[2];
  const float* Wv  = (const float*)d_in[3];
  const float* Wo  = (const float*)d_in[4];
  const float* bo  = (const float*)d_in[5];

  char* ws = (char*)d_ws;
  size_t off = 0;
  __hip_bfloat16* hidB = (__hip_bfloat16*)(ws + off); off += (size_t)ROWS * HID * 2;
  __hip_bfloat16* WqB  = (__hip_bfloat16*)(ws + off); off += (size_t)HID * HID * 2;
  __hip_bfloat16* WkB  = (__hip_bfloat16*)(ws + off); off += (size_t)HID * HID * 2;
  __hip_bfloat16* WvB  = (__hip_bfloat16*)(ws + off); off += (size_t)HID * HID * 2;
  __hip_bfloat16* WoB  = (__hip_bfloat16*)(ws + off); off += (size_t)HID * HID * 2;
  __hip_bfloat16* Qr   = (__hip_bfloat16*)(ws + off); off += (size_t)ROWS * HID * 2;
  __hip_bfloat16* Kr   = (__hip_bfloat16*)(ws + off); off += (size_t)ROWS * HID * 2;
  __hip_bfloat16* vlin = (__hip_bfloat16*)(ws + off); off += (size_t)ROWS * HID * 2;
  __hip_bfloat16* Vt   = hidB;       // alias: hidden bf16 dead after QKV GEMMs
  __hip_bfloat16* attn = vlin;       // alias: vlin dead after transpose_v

  castk<<<(ROWS * HID / 8 + 255) / 256, 256, 0, stream>>>(hid, hidB, ROWS * HID / 8);
  castk<<<(HID * HID / 8 + 255) / 256, 256, 0, stream>>>(Wq, WqB, HID * HID / 8);
  castk<<<(HID * HID / 8 + 255) / 256, 256, 0, stream>>>(Wk, WkB, HID * HID / 8);
  castk<<<(HID * HID / 8 + 255) / 256, 256, 0, stream>>>(Wv, WvB, HID * HID / 8);
  castk<<<(HID * HID / 8 + 255) / 256, 256, 0, stream>>>(Wo, WoB, HID * HID / 8);

  dim3 gg(HID / 128, ROWS / 128);   // 16 x 64
  gemm_nt<1><<<gg, 256, 0, stream>>>(hidB, WqB, nullptr, (void*)Qr, ROWS, HID);
  gemm_nt<2><<<gg, 256, 0, stream>>>(hidB, WkB, nullptr, (void*)Kr, ROWS, HID);
  gemm_nt<0><<<gg, 256, 0, stream>>>(hidB, WvB, nullptr, (void*)vlin, ROWS, HID);

  transpose_v<<<BATCH * NH * (SEQ / 64), 256, 0, stream>>>(vlin, Vt);

  flash<<<BATCH * NH * (SEQ / 128), 512, 0, stream>>>(Qr, Kr, Vt, attn);

  gemm_nt<3><<<gg, 256, 0, stream>>>(attn, WoB, bo, d_out, ROWS, HID);
}

// Round 3
// 711.007 us; speedup vs baseline: 1.1816x; 1.1385x over previous
//
#include <hip/hip_runtime.h>
#include <hip/hip_bf16.h>
#include <stdint.h>

#define HID 2048
#define SEQ 4096
#define BATCH 2
#define NH 32
#define HD 64
#define ROWS (BATCH*SEQ)
#define LOCAL_H 30
#define LOG2E 1.4426950408889634f

typedef __attribute__((ext_vector_type(4))) float f32x4;
typedef __attribute__((ext_vector_type(16))) float f32x16;
typedef __attribute__((ext_vector_type(8))) short s16x8;
typedef __attribute__((ext_vector_type(4))) unsigned int u32x4;

__device__ __forceinline__ void g2l16(const void* g, void* l) {
  __builtin_amdgcn_global_load_lds((__attribute__((address_space(1))) void*)(g),
                                   (__attribute__((address_space(3))) void*)(l), 16, 0, 0);
}

__device__ __forceinline__ unsigned pk2(float a, float b) {
  union { __hip_bfloat16 h; unsigned short u; } x, y;
  x.h = __float2bfloat16(a); y.h = __float2bfloat16(b);
  return ((unsigned)y.u << 16) | x.u;
}

// ---------------- cast f32 -> bf16, 8 elems/thread ----------------
__global__ __launch_bounds__(256) void castk(const float* __restrict__ s,
                                             __hip_bfloat16* __restrict__ d, int n8) {
  int i = blockIdx.x * 256 + threadIdx.x;
  if (i >= n8) return;
  const f32x4* sp = (const f32x4*)(s) + (size_t)i * 2;
  f32x4 a = sp[0], b = sp[1];
  __hip_bfloat16 t[8];
#pragma unroll
  for (int j = 0; j < 4; j++) { t[j] = __float2bfloat16(a[j]); t[j+4] = __float2bfloat16(b[j]); }
  *(s16x8*)(d + (size_t)i * 8) = *(const s16x8*)t;
}

// ---------------- NT GEMM: C[M][N] = A[M][K] * W[N][K]^T ----------------
// MODE 0: bf16 out row-major; MODE 1: RoPE + 0.125*log2e (Q, log2 domain);
// MODE 2: RoPE (K); MODE 3: f32 out + bias
template<int MODE>
__global__ __launch_bounds__(256) void gemm_nt(const __hip_bfloat16* __restrict__ A,
                                               const __hip_bfloat16* __restrict__ W,
                                               const float* __restrict__ bias,
                                               void* __restrict__ outp, int M, int K) {
  __shared__ __hip_bfloat16 As[128 * 64];
  __shared__ __hip_bfloat16 Bs[128 * 64];
  const int tid = threadIdx.x;
  const int lane = tid & 63, wv = tid >> 6;
  const int wr = wv >> 1, wc = wv & 1;
  const int g = lane >> 4, ln = lane & 15;
  const int m0 = blockIdx.y * 128, n0 = blockIdx.x * 128;

  f32x4 acc[4][4];
#pragma unroll
  for (int i = 0; i < 4; i++)
#pragma unroll
    for (int j = 0; j < 4; j++) acc[i][j] = (f32x4)0.f;

  for (int kt = 0; kt < K; kt += 64) {
    __syncthreads();
#pragma unroll
    for (int i = 0; i < 4; i++) {
      int c = i * 256 + tid;
      int row = c >> 3, slot = c & 7;
      int colE = ((slot ^ (row & 7)) * 8);
      g2l16(A + (size_t)(m0 + row) * K + kt + colE,
            (void*)(As + (i * 256 + wv * 64) * 8));
    }
#pragma unroll
    for (int i = 0; i < 4; i++) {
      int c = i * 256 + tid;
      int row = c >> 3, slot = c & 7;
      int colE = ((slot ^ (row & 7)) * 8);
      g2l16(W + (size_t)(n0 + row) * K + kt + colE,
            (void*)(Bs + (i * 256 + wv * 64) * 8));
    }
    __syncthreads();
#pragma unroll
    for (int ks = 0; ks < 2; ks++) {
      s16x8 af[4], bfr[4];
#pragma unroll
      for (int i = 0; i < 4; i++) {
        int row = wr * 64 + i * 16 + ln;
        af[i] = *(const s16x8*)(As + row * 64 + (((ks * 4 + g) ^ (row & 7)) * 8));
      }
#pragma unroll
      for (int j = 0; j < 4; j++) {
        int row = wc * 64 + j * 16 + ln;
        bfr[j] = *(const s16x8*)(Bs + row * 64 + (((ks * 4 + g) ^ (row & 7)) * 8));
      }
#pragma unroll
      for (int i = 0; i < 4; i++)
#pragma unroll
        for (int j = 0; j < 4; j++)
          acc[i][j] = __builtin_amdgcn_mfma_f32_16x16x32_bf16(af[i], bfr[j], acc[i][j], 0, 0, 0);
    }
  }

#pragma unroll
  for (int i = 0; i < 4; i++) {
#pragma unroll
    for (int r = 0; r < 4; r++) {
      int grow = m0 + wr * 64 + i * 16 + g * 4 + r;
      if constexpr (MODE == 0) {
        __hip_bfloat16* o = (__hip_bfloat16*)outp + (size_t)grow * HID + n0 + wc * 64;
#pragma unroll
        for (int j = 0; j < 4; j++) o[j * 16 + ln] = __float2bfloat16(acc[i][j][r]);
      } else if constexpr (MODE == 3) {
        float* o = (float*)outp + (size_t)grow * HID + n0 + wc * 64;
#pragma unroll
        for (int j = 0; j < 4; j++)
          o[j * 16 + ln] = acc[i][j][r] + bias[n0 + wc * 64 + j * 16 + ln];
      } else {
        int b = grow >> 12, l = grow & (SEQ - 1);
        int h = (n0 >> 6) + wc;
        __hip_bfloat16* o = (__hip_bfloat16*)outp + ((size_t)(b * NH + h) * SEQ + l) * HD;
#pragma unroll
        for (int j = 0; j < 2; j++) {
          int d = j * 16 + ln;
          float x1 = acc[i][j][r], x2 = acc[i][j + 2][r];
          float ang = (float)l * exp2f((float)d * -0.41524101186091903f);
          float sn, cs;
          sincosf(ang, &sn, &cs);
          float o1 = x1 * cs - x2 * sn;
          float o2 = x2 * cs + x1 * sn;
          if constexpr (MODE == 1) { o1 *= 0.125f * LOG2E; o2 *= 0.125f * LOG2E; }
          o[d]      = __float2bfloat16(o1);
          o[d + 32] = __float2bfloat16(o2);
        }
      }
    }
  }
}

// ---------------- V transpose ----------------
__global__ __launch_bounds__(256) void transpose_v(const __hip_bfloat16* __restrict__ vlin,
                                                   __hip_bfloat16* __restrict__ vt) {
  __shared__ __hip_bfloat16 T[64][72];
  int blk = blockIdx.x;
  int l0 = (blk & 63) * 64;
  int bh = blk >> 6;
  int tid = threadIdx.x;
  {
    int l = tid >> 2, dq = (tid & 3) * 16;
    const __hip_bfloat16* src = vlin + (size_t)((bh >> 5) * SEQ + l0 + l) * HID + (bh & 31) * HD + dq;
    s16x8 v0 = *(const s16x8*)(src);
    s16x8 v1 = *(const s16x8*)(src + 8);
    *(s16x8*)&T[l][dq] = v0;
    *(s16x8*)&T[l][dq + 8] = v1;
  }
  __syncthreads();
  {
    int d = tid >> 2, lq = (tid & 3) * 16;
    __hip_bfloat16 tmp[16];
#pragma unroll
    for (int e = 0; e < 16; e++) tmp[e] = T[lq + e][d];
    __hip_bfloat16* dst = vt + ((size_t)bh * HD + d) * SEQ + l0 + lq;
    *(s16x8*)dst = *(const s16x8*)tmp;
    *(s16x8*)(dst + 8) = *(const s16x8*)(tmp + 8);
  }
}

// ---------------- flash attention: 32x32 swapped-operand, in-register softmax ----------------
// Q pre-scaled by 0.125*log2e (log2 domain). Q,K: [bh][l][64]; Vt: [bh][64][SEQ]
// 8 waves x 32 q-rows = 256 q/block. KVBLK=64 double-buffered. S^T = mfma(K,Q): lane owns q=ln32.
__global__ __launch_bounds__(512, 4) void flash(const __hip_bfloat16* __restrict__ Q,
                                                const __hip_bfloat16* __restrict__ Kk,
                                                const __hip_bfloat16* __restrict__ Vt,
                                                __hip_bfloat16* __restrict__ attn) {
  __shared__ __hip_bfloat16 Ks[2][64 * 64];
  __shared__ __hip_bfloat16 Vs[2][64 * 64];

  // balanced bijective XCD swizzle: bh=8x+y -> xcd (x+y)&7; global heads (30,31,62,63)
  // land on xcds 1,2,5,6. Tiles issued long-first (qt descending).
  int blk = blockIdx.x;
  int c = blk & 7, t = blk >> 3;          // t 0..127
  int j = t >> 4, qtl = 15 - (t & 15);
  int bh = j * 8 + ((c - j) & 7);
  int h = bh & 31;
  int q0 = qtl * 256;

  int tid = threadIdx.x, lane = tid & 63, wv = tid >> 6;
  int ln32 = lane & 31, hi = lane >> 5;

  int ks0 = 0;
  if (h < LOCAL_H) { ks0 = (q0 >> 10) * 1024 - 512; if (ks0 < 0) ks0 = 0; }
  int nch = (q0 + 256 - ks0) >> 6;

  int qw0 = q0 + wv * 32;        // wave's first q row
  int qg = qw0 + ln32;           // lane's q row (sequence pos)

  // Q fragments: B-operand, col=q, k-slice t: d = t*16 + hi*8 + j
  const __hip_bfloat16* qb = Q + ((size_t)bh * SEQ + qg) * HD + hi * 8;
  s16x8 qf[4];
#pragma unroll
  for (int tt = 0; tt < 4; tt++) qf[tt] = *(const s16x8*)(qb + tt * 16);

  float mrow = -3.0e38f, lrow = 0.f;
  f32x16 o0 = (f32x16)0.f, o1 = (f32x16)0.f;

  const int srow = tid >> 3, sslot = tid & 7;
  const int scolE = (sslot ^ (srow & 7)) * 8;

  { // prologue: stage chunk 0 into buffer 0
    int kc = ks0;
    g2l16(Kk + ((size_t)bh * SEQ + kc + srow) * HD + scolE, (void*)(&Ks[0][0] + wv * 512));
    g2l16(Vt + ((size_t)bh * HD + srow) * SEQ + kc + scolE, (void*)(&Vs[0][0] + wv * 512));
  }

  int cur = 0;
  for (int ci = 0; ci < nch; ci++) {
    int kc = ks0 + ci * 64;
    if (ci + 1 < nch) {
      int kn = kc + 64;
      g2l16(Kk + ((size_t)bh * SEQ + kn + srow) * HD + scolE, (void*)(&Ks[cur ^ 1][0] + wv * 512));
      g2l16(Vt + ((size_t)bh * HD + srow) * SEQ + kn + scolE, (void*)(&Vs[cur ^ 1][0] + wv * 512));
      asm volatile("s_waitcnt vmcnt(2)" ::: "memory");
    } else {
      asm volatile("s_waitcnt vmcnt(0)" ::: "memory");
    }
    __builtin_amdgcn_s_barrier();
    __builtin_amdgcn_sched_barrier(0);

    if (kc <= qw0 + 31) {        // wave-uniform skip of fully-masked chunks
      const __hip_bfloat16* Kc = &Ks[cur][0];
      const __hip_bfloat16* Vc = &Vs[cur][0];

      // S^T = K * Q^T : s0 = kv rows 0-31, s1 = kv rows 32-63; col = q
      f32x16 s0 = (f32x16)0.f, s1 = (f32x16)0.f;
      __builtin_amdgcn_s_setprio(1);
#pragma unroll
      for (int tt = 0; tt < 4; tt++) {
        int sl = ((2 * tt + hi) ^ (ln32 & 7)) * 8;
        s16x8 ka = *(const s16x8*)(Kc + ln32 * 64 + sl);
        s0 = __builtin_amdgcn_mfma_f32_32x32x16_bf16(ka, qf[tt], s0, 0, 0, 0);
        s16x8 kb = *(const s16x8*)(Kc + (32 + ln32) * 64 + sl);
        s1 = __builtin_amdgcn_mfma_f32_32x32x16_bf16(kb, qf[tt], s1, 0, 0, 0);
      }
      __builtin_amdgcn_s_setprio(0);

      if (kc + 63 > qw0) {       // diagonal: mask kv > q
#pragma unroll
        for (int r = 0; r < 16; r++) {
          int kv0 = kc + (r & 3) + 8 * (r >> 2) + 4 * hi;
          if (kv0 > qg) s0[r] = -1.0e30f;
          if (kv0 + 32 > qg) s1[r] = -1.0e30f;
        }
      }

      // in-register online softmax (log2 domain); lane pair (c, c+32) share q
      float pm = s0[0];
#pragma unroll
      for (int r = 1; r < 16; r++) pm = fmaxf(pm, s0[r]);
#pragma unroll
      for (int r = 0; r < 16; r++) pm = fmaxf(pm, s1[r]);
      pm = fmaxf(pm, __shfl_xor(pm, 32));
      float mnew = fmaxf(mrow, pm);
      float corr = exp2f(mrow - mnew);
      float ps = 0.f;
#pragma unroll
      for (int r = 0; r < 16; r++) { float p = exp2f(s0[r] - mnew); s0[r] = p; ps += p; }
#pragma unroll
      for (int r = 0; r < 16; r++) { float p = exp2f(s1[r] - mnew); s1[r] = p; ps += p; }
      ps += __shfl_xor(ps, 32);
      lrow = lrow * corr + ps;
      mrow = mnew;
#pragma unroll
      for (int r = 0; r < 16; r++) { o0[r] *= corr; o1[r] *= corr; }

      // build P^T B-fragments in-register (per kv-slice of 16)
      s16x8 bf0, bf1, bf2, bf3;
#define MK_BFRAG(dst, tile, base)                                          \
      {                                                                    \
        unsigned X = pk2(tile[base + 0], tile[base + 1]);                  \
        unsigned Y = pk2(tile[base + 2], tile[base + 3]);                  \
        unsigned Z = pk2(tile[base + 4], tile[base + 5]);                  \
        unsigned W = pk2(tile[base + 6], tile[base + 7]);                  \
        unsigned Xs = __shfl_xor(X, 32), Ys = __shfl_xor(Y, 32);           \
        unsigned Zs = __shfl_xor(Z, 32), Ws = __shfl_xor(W, 32);           \
        u32x4 wq;                                                          \
        wq.x = hi ? Zs : X; wq.y = hi ? Ws : Y;                            \
        wq.z = hi ? Z : Xs; wq.w = hi ? W : Ys;                            \
        dst = __builtin_bit_cast(s16x8, wq);                               \
      }
      MK_BFRAG(bf0, s0, 0)
      MK_BFRAG(bf1, s0, 8)
      MK_BFRAG(bf2, s1, 0)
      MK_BFRAG(bf3, s1, 8)
#undef MK_BFRAG

      // O^T += V^T * P : o0 = d rows 0-31, o1 = d rows 32-63
      __builtin_amdgcn_s_setprio(1);
#pragma unroll
      for (int ss = 0; ss < 4; ss++) {
        int sl = ((2 * ss + hi) ^ (ln32 & 7)) * 8;
        s16x8 bfr = (ss == 0) ? bf0 : (ss == 1) ? bf1 : (ss == 2) ? bf2 : bf3;
        s16x8 va = *(const s16x8*)(Vc + ln32 * 64 + sl);
        o0 = __builtin_amdgcn_mfma_f32_32x32x16_bf16(va, bfr, o0, 0, 0, 0);
        s16x8 vb = *(const s16x8*)(Vc + (32 + ln32) * 64 + sl);
        o1 = __builtin_amdgcn_mfma_f32_32x32x16_bf16(vb, bfr, o1, 0, 0, 0);
      }
      __builtin_amdgcn_s_setprio(0);
    }

    __builtin_amdgcn_sched_barrier(0);
    asm volatile("s_waitcnt lgkmcnt(0)" ::: "memory");
    __builtin_amdgcn_s_barrier();
    cur ^= 1;
  }

  // epilogue: normalize (per-lane, q-uniform) and scatter packed pairs
  float linv = 1.0f / lrow;
  int orow = (bh >> 5) * SEQ + qg;
  __hip_bfloat16* ob = attn + (size_t)orow * HID + h * HD;
#pragma unroll
  for (int rp = 0; rp < 16; rp += 2) {
    int d0 = (rp & 3) + 8 * (rp >> 2) + 4 * hi;
    *(unsigned*)(ob + d0)      = pk2(o0[rp] * linv, o0[rp + 1] * linv);
    *(unsigned*)(ob + 32 + d0) = pk2(o1[rp] * linv, o1[rp + 1] * linv);
  }
}

extern "C" void kernel_launch(void* const* d_in, const int* in_sizes, int n_in,
                              void* d_out, int out_size, void* d_ws, size_t ws_size,
                              hipStream_t stream) {
  (void)in_sizes; (void)n_in; (void)out_size; (void)ws_size;
  const float* hid = (const float*)d_in[0];
  const float* Wq  = (const float*)d_in[1];
  const float* Wk  = (const float*)d_in[2];
  const float* Wv  = (const float*)d_in[3];
  const float* Wo  = (const float*)d_in[4];
  const float* bo  = (const float*)d_in[5];

  char* ws = (char*)d_ws;
  size_t off = 0;
  __hip_bfloat16* hidB = (__hip_bfloat16*)(ws + off); off += (size_t)ROWS * HID * 2;
  __hip_bfloat16* WqB  = (__hip_bfloat16*)(ws + off); off += (size_t)HID * HID * 2;
  __hip_bfloat16* WkB  = (__hip_bfloat16*)(ws + off); off += (size_t)HID * HID * 2;
  __hip_bfloat16* WvB  = (__hip_bfloat16*)(ws + off); off += (size_t)HID * HID * 2;
  __hip_bfloat16* WoB  = (__hip_bfloat16*)(ws + off); off += (size_t)HID * HID * 2;
  __hip_bfloat16* Qr   = (__hip_bfloat16*)(ws + off); off += (size_t)ROWS * HID * 2;
  __hip_bfloat16* Kr   = (__hip_bfloat16*)(ws + off); off += (size_t)ROWS * HID * 2;
  __hip_bfloat16* vlin = (__hip_bfloat16*)(ws + off); off += (size_t)ROWS * HID * 2;
  __hip_bfloat16* Vt   = hidB;       // alias: hidden bf16 dead after QKV GEMMs
  __hip_bfloat16* attn = vlin;       // alias: vlin dead after transpose_v

  castk<<<(ROWS * HID / 8 + 255) / 256, 256, 0, stream>>>(hid, hidB, ROWS * HID / 8);
  castk<<<(HID * HID / 8 + 255) / 256, 256, 0, stream>>>(Wq, WqB, HID * HID / 8);
  castk<<<(HID * HID / 8 + 255) / 256, 256, 0, stream>>>(Wk, WkB, HID * HID / 8);
  castk<<<(HID * HID / 8 + 255) / 256, 256, 0, stream>>>(Wv, WvB, HID * HID / 8);
  castk<<<(HID * HID / 8 + 255) / 256, 256, 0, stream>>>(Wo, WoB, HID * HID / 8);

  dim3 gg(HID / 128, ROWS / 128);   // 16 x 64
  gemm_nt<1><<<gg, 256, 0, stream>>>(hidB, WqB, nullptr, (void*)Qr, ROWS, HID);
  gemm_nt<2><<<gg, 256, 0, stream>>>(hidB, WkB, nullptr, (void*)Kr, ROWS, HID);
  gemm_nt<0><<<gg, 256, 0, stream>>>(hidB, WvB, nullptr, (void*)vlin, ROWS, HID);

  transpose_v<<<BATCH * NH * (SEQ / 64), 256, 0, stream>>>(vlin, Vt);

  flash<<<BATCH * NH * (SEQ / 256), 512, 0, stream>>>(Qr, Kr, Vt, attn);

  gemm_nt<3><<<gg, 256, 0, stream>>>(attn, WoB, bo, d_out, ROWS, HID);
}

// Round 4
// 654.108 us; speedup vs baseline: 1.2844x; 1.0870x over previous
//
#include <hip/hip_runtime.h>
#include <hip/hip_bf16.h>
#include <stdint.h>

#define HID 2048
#define SEQ 4096
#define BATCH 2
#define NH 32
#define HD 64
#define ROWS (BATCH*SEQ)
#define LOCAL_H 30
#define LOG2E 1.4426950408889634f
#define NT 32              // K tiles of 64 in 2048

typedef __attribute__((ext_vector_type(4))) float f32x4;
typedef __attribute__((ext_vector_type(16))) float f32x16;
typedef __attribute__((ext_vector_type(8))) short s16x8;
typedef __attribute__((ext_vector_type(4))) unsigned int u32x4;

__device__ __forceinline__ void g2l16(const void* g, void* l) {
  __builtin_amdgcn_global_load_lds((__attribute__((address_space(1))) void*)(g),
                                   (__attribute__((address_space(3))) void*)(l), 16, 0, 0);
}

__device__ __forceinline__ unsigned pk2(float a, float b) {
  union { __hip_bfloat16 h; unsigned short u; } x, y;
  x.h = __float2bfloat16(a); y.h = __float2bfloat16(b);
  return ((unsigned)y.u << 16) | x.u;
}

// ---------------- cast f32 -> bf16 ----------------
__global__ __launch_bounds__(256) void castk(const float* __restrict__ s,
                                             __hip_bfloat16* __restrict__ d, int n8) {
  int i = blockIdx.x * 256 + threadIdx.x;
  if (i >= n8) return;
  const f32x4* sp = (const f32x4*)(s) + (size_t)i * 2;
  f32x4 a = sp[0], b = sp[1];
  __hip_bfloat16 t[8];
#pragma unroll
  for (int j = 0; j < 4; j++) { t[j] = __float2bfloat16(a[j]); t[j+4] = __float2bfloat16(b[j]); }
  *(s16x8*)(d + (size_t)i * 8) = *(const s16x8*)t;
}

// ---------------- 256x256 deep-pipelined NT GEMM ----------------
// C[M][N] = A[M][K] * W[N][K]^T, M=8192 N=2048 K=2048.
// 8 waves (2M x 4N); wave tile 128x64: A-half interleaved (rows mi*128+wm*64),
// B-half fixed (cols (wn>>1)*128+(wn&1)*64). 4 phases/K-tile, 1 barrier/phase,
// stage order A0,B0,B1,A1 of tile t+1, vmcnt(4) counted wait.
// MODE 0: bf16 out; MODE 1: RoPE+0.125*log2e -> Q scatter; MODE 2: RoPE -> K scatter;
// MODE 3: f32 out + bias.
template<int MODE>
__global__ __launch_bounds__(512) void gemm256(const __hip_bfloat16* __restrict__ A,
                                               const __hip_bfloat16* __restrict__ W,
                                               const float* __restrict__ bias,
                                               void* __restrict__ outp) {
  __shared__ __hip_bfloat16 lds[2][4][128 * 64];   // [buf][A0,A1,B0,B1][16KB]
  const int tid = threadIdx.x;
  const int lane = tid & 63, wv = tid >> 6;
  const int wm = wv >> 2, wn = wv & 3;
  const int g = lane >> 4, ln = lane & 15;
  const int m0 = blockIdx.y * 256, n0 = blockIdx.x * 256;

  const int srow = tid >> 3, sslot = tid & 7;
  const int scolE = (sslot ^ (srow & 7)) * 8;
  const int srow2 = (512 + tid) >> 3, sslot2 = tid & 7;       // q=1: rows 64..127
  const int scolE2 = (sslot2 ^ (srow2 & 7)) * 8;

  // stage one 128-row x 64-col half-tile (2 x g2l16 per thread)
#define STAGE(srcbase, ldK, kt, region)                                         \
  {                                                                             \
    g2l16((srcbase) + (size_t)(srow) * (ldK) + (kt) + scolE,                    \
          (void*)(&lds[0][0][0] + (region) * 8192 + wv * 512));                 \
    g2l16((srcbase) + (size_t)(srow2) * (ldK) + (kt) + scolE2,                  \
          (void*)(&lds[0][0][0] + (region) * 8192 + 4096 + wv * 512));          \
  }

  f32x4 acc[8][4];
#pragma unroll
  for (int i = 0; i < 8; i++)
#pragma unroll
    for (int j = 0; j < 4; j++) acc[i][j] = (f32x4)0.f;

  // prologue: tile 0 into buf 0, order A0,B0,B1,A1
  STAGE(A + (size_t)m0 * HID,           HID, 0, 0);
  STAGE(W + (size_t)n0 * HID,           HID, 0, 2);
  STAGE(W + (size_t)(n0 + 128) * HID,   HID, 0, 3);
  STAGE(A + (size_t)(m0 + 128) * HID,   HID, 0, 1);

  for (int t = 0; t < NT; ++t) {
    const int buf = t & 1, nbuf = buf ^ 1;
    const int ktn = (t + 1) * 64;
    const bool pre = (t + 1 < NT);
#pragma unroll
    for (int p = 0; p < 4; ++p) {
      if (pre) {
        if (p == 0) STAGE(A + (size_t)m0 * HID,         HID, ktn, nbuf * 4 + 0)
        if (p == 1) STAGE(W + (size_t)n0 * HID,         HID, ktn, nbuf * 4 + 2)
        if (p == 2) STAGE(W + (size_t)(n0 + 128) * HID, HID, ktn, nbuf * 4 + 3)
        if (p == 3) STAGE(A + (size_t)(m0 + 128) * HID, HID, ktn, nbuf * 4 + 1)
        asm volatile("s_waitcnt vmcnt(4)" ::: "memory");
      } else if (p == 0) {
        asm volatile("s_waitcnt vmcnt(0)" ::: "memory");
      }
      __builtin_amdgcn_sched_barrier(0);
      __builtin_amdgcn_s_barrier();
      __builtin_amdgcn_sched_barrier(0);

      const int mi = p >> 1, ni = p & 1;
      const __hip_bfloat16* Ah = &lds[buf][mi][0];
      const __hip_bfloat16* Bh = &lds[buf][2 + (wn >> 1)][0];
      s16x8 af[4][2], bfv[2][2];
#pragma unroll
      for (int st = 0; st < 4; st++) {
        int row = wm * 64 + st * 16 + ln;
#pragma unroll
        for (int ks = 0; ks < 2; ks++)
          af[st][ks] = *(const s16x8*)(Ah + row * 64 + (((ks * 4 + g) ^ (row & 7)) * 8));
      }
#pragma unroll
      for (int st2 = 0; st2 < 2; st2++) {
        int row = (wn & 1) * 64 + ni * 32 + st2 * 16 + ln;
#pragma unroll
        for (int ks = 0; ks < 2; ks++)
          bfv[st2][ks] = *(const s16x8*)(Bh + row * 64 + (((ks * 4 + g) ^ (row & 7)) * 8));
      }
      __builtin_amdgcn_s_setprio(1);
#pragma unroll
      for (int st = 0; st < 4; st++)
#pragma unroll
        for (int st2 = 0; st2 < 2; st2++)
#pragma unroll
          for (int ks = 0; ks < 2; ks++)
            acc[mi * 4 + st][ni * 2 + st2] =
              __builtin_amdgcn_mfma_f32_16x16x32_bf16(af[st][ks], bfv[st2][ks],
                                                      acc[mi * 4 + st][ni * 2 + st2], 0, 0, 0);
      __builtin_amdgcn_s_setprio(0);
    }
  }
#undef STAGE

  const int n0c = n0 + (wn >> 1) * 128 + (wn & 1) * 64;
#pragma unroll
  for (int am = 0; am < 8; am++) {
#pragma unroll
    for (int r = 0; r < 4; r++) {
      int grow = m0 + (am >> 2) * 128 + wm * 64 + (am & 3) * 16 + g * 4 + r;
      if constexpr (MODE == 0) {
        __hip_bfloat16* o = (__hip_bfloat16*)outp + (size_t)grow * HID + n0c;
#pragma unroll
        for (int j = 0; j < 4; j++) o[j * 16 + ln] = __float2bfloat16(acc[am][j][r]);
      } else if constexpr (MODE == 3) {
        float* o = (float*)outp + (size_t)grow * HID + n0c;
#pragma unroll
        for (int j = 0; j < 4; j++)
          o[j * 16 + ln] = acc[am][j][r] + bias[n0c + j * 16 + ln];
      } else {
        int b = grow >> 12, l = grow & (SEQ - 1);
        int h = n0c >> 6;
        __hip_bfloat16* o = (__hip_bfloat16*)outp + ((size_t)(b * NH + h) * SEQ + l) * HD;
#pragma unroll
        for (int j = 0; j < 2; j++) {
          int d = j * 16 + ln;
          float x1 = acc[am][j][r], x2 = acc[am][j + 2][r];
          float ang = (float)l * exp2f((float)d * -0.41524101186091903f);
          float sn, cs;
          sincosf(ang, &sn, &cs);
          float o1 = x1 * cs - x2 * sn;
          float o2 = x2 * cs + x1 * sn;
          if constexpr (MODE == 1) { o1 *= 0.125f * LOG2E; o2 *= 0.125f * LOG2E; }
          o[d]      = __float2bfloat16(o1);
          o[d + 32] = __float2bfloat16(o2);
        }
      }
    }
  }
}

// ---------------- V transpose ----------------
__global__ __launch_bounds__(256) void transpose_v(const __hip_bfloat16* __restrict__ vlin,
                                                   __hip_bfloat16* __restrict__ vt) {
  __shared__ __hip_bfloat16 T[64][72];
  int blk = blockIdx.x;
  int l0 = (blk & 63) * 64;
  int bh = blk >> 6;
  int tid = threadIdx.x;
  {
    int l = tid >> 2, dq = (tid & 3) * 16;
    const __hip_bfloat16* src = vlin + (size_t)((bh >> 5) * SEQ + l0 + l) * HID + (bh & 31) * HD + dq;
    s16x8 v0 = *(const s16x8*)(src);
    s16x8 v1 = *(const s16x8*)(src + 8);
    *(s16x8*)&T[l][dq] = v0;
    *(s16x8*)&T[l][dq + 8] = v1;
  }
  __syncthreads();
  {
    int d = tid >> 2, lq = (tid & 3) * 16;
    __hip_bfloat16 tmp[16];
#pragma unroll
    for (int e = 0; e < 16; e++) tmp[e] = T[lq + e][d];
    __hip_bfloat16* dst = vt + ((size_t)bh * HD + d) * SEQ + l0 + lq;
    *(s16x8*)dst = *(const s16x8*)tmp;
    *(s16x8*)(dst + 8) = *(const s16x8*)(tmp + 8);
  }
}

// ---------------- flash attention: stage 128 keys, compute 2x64 sub-steps ----------------
// Q pre-scaled by 0.125*log2e (log2 domain). Q,K: [bh][l][64]; Vt: [bh][64][SEQ]
// 8 waves x 32 q = 256 q/block. S^T = mfma(K,Q): lane owns q. V in LDS as [64 d][128 kv].
__global__ __launch_bounds__(512, 4) void flash(const __hip_bfloat16* __restrict__ Q,
                                                const __hip_bfloat16* __restrict__ Kk,
                                                const __hip_bfloat16* __restrict__ Vt,
                                                __hip_bfloat16* __restrict__ attn) {
  __shared__ __hip_bfloat16 Ks[2][128 * 64];
  __shared__ __hip_bfloat16 Vs[2][64 * 128];

  int blk = blockIdx.x;
  int c = blk & 7, t = blk >> 3;
  int j = t >> 4, qtl = 15 - (t & 15);
  int bh = j * 8 + ((c - j) & 7);
  int h = bh & 31;
  int q0 = qtl * 256;

  int tid = threadIdx.x, lane = tid & 63, wv = tid >> 6;
  int ln32 = lane & 31, hi = lane >> 5;

  int ks0 = 0;
  if (h < LOCAL_H) { ks0 = (q0 >> 10) * 1024 - 512; if (ks0 < 0) ks0 = 0; }
  int nch = (q0 + 256 - ks0) >> 7;     // 128-wide chunks (span always multiple of 256)

  int qw0 = q0 + wv * 32;
  int qg = qw0 + ln32;

  const __hip_bfloat16* qb = Q + ((size_t)bh * SEQ + qg) * HD + hi * 8;
  s16x8 qf[4];
#pragma unroll
  for (int tt = 0; tt < 4; tt++) qf[tt] = *(const s16x8*)(qb + tt * 16);

  float mrow = -3.0e38f, lrow = 0.f;
  f32x16 o0 = (f32x16)0.f, o1 = (f32x16)0.f;

  // K staging: 1024 16B-chunks; V staging: [64][128] layout, 16 slots/row
  const int krow = tid >> 3, kslot = tid & 7;
  const int kcolE = (kslot ^ (krow & 7)) * 8;
  const int krow2 = (512 + tid) >> 3;
  const int kcolE2 = (kslot ^ (krow2 & 7)) * 8;
  const int vrow = tid >> 4, vslot = tid & 15;
  const int vcolE = (vslot ^ (vrow & 15)) * 8;
  const int vrow2 = (512 + tid) >> 4;
  const int vcolE2 = (vslot ^ (vrow2 & 15)) * 8;

#define STAGEKV(b, kc)                                                                     \
  {                                                                                        \
    g2l16(Kk + ((size_t)bh * SEQ + (kc) + krow) * HD + kcolE,  (void*)(&Ks[b][0] + wv * 512));        \
    g2l16(Kk + ((size_t)bh * SEQ + (kc) + krow2) * HD + kcolE2,(void*)(&Ks[b][0] + 4096 + wv * 512)); \
    g2l16(Vt + ((size_t)bh * HD + vrow) * SEQ + (kc) + vcolE,  (void*)(&Vs[b][0] + wv * 512));        \
    g2l16(Vt + ((size_t)bh * HD + vrow2) * SEQ + (kc) + vcolE2,(void*)(&Vs[b][0] + 4096 + wv * 512)); \
  }

  STAGEKV(0, ks0)

  int cur = 0;
  for (int ci = 0; ci < nch; ci++) {
    int kc = ks0 + ci * 128;
    if (ci + 1 < nch) {
      STAGEKV(cur ^ 1, kc + 128)
      asm volatile("s_waitcnt vmcnt(4)" ::: "memory");
    } else {
      asm volatile("s_waitcnt vmcnt(0)" ::: "memory");
    }
    __builtin_amdgcn_s_barrier();
    __builtin_amdgcn_sched_barrier(0);

#pragma unroll
    for (int kvh = 0; kvh < 2; kvh++) {
      int kcs = kc + kvh * 64;
      if (kcs <= qw0 + 31) {
        const __hip_bfloat16* Kc = &Ks[cur][0] + kvh * 64 * 64;
        const __hip_bfloat16* Vc = &Vs[cur][0];

        f32x16 s0 = (f32x16)0.f, s1 = (f32x16)0.f;
        __builtin_amdgcn_s_setprio(1);
#pragma unroll
        for (int tt = 0; tt < 4; tt++) {
          int sl0 = ((2 * tt + hi) ^ (ln32 & 7)) * 8;
          s16x8 ka = *(const s16x8*)(Kc + ln32 * 64 + sl0);
          s0 = __builtin_amdgcn_mfma_f32_32x32x16_bf16(ka, qf[tt], s0, 0, 0, 0);
          s16x8 kb = *(const s16x8*)(Kc + (32 + ln32) * 64 + sl0);
          s1 = __builtin_amdgcn_mfma_f32_32x32x16_bf16(kb, qf[tt], s1, 0, 0, 0);
        }
        __builtin_amdgcn_s_setprio(0);

        if (kcs + 63 > qw0) {
#pragma unroll
          for (int r = 0; r < 16; r++) {
            int kv0 = kcs + (r & 3) + 8 * (r >> 2) + 4 * hi;
            if (kv0 > qg) s0[r] = -1.0e30f;
            if (kv0 + 32 > qg) s1[r] = -1.0e30f;
          }
        }

        float pm = s0[0];
#pragma unroll
        for (int r = 1; r < 16; r++) pm = fmaxf(pm, s0[r]);
#pragma unroll
        for (int r = 0; r < 16; r++) pm = fmaxf(pm, s1[r]);
        pm = fmaxf(pm, __shfl_xor(pm, 32));
        float mnew = fmaxf(mrow, pm);
        float ps = 0.f;
#pragma unroll
        for (int r = 0; r < 16; r++) { float p = exp2f(s0[r] - mnew); s0[r] = p; ps += p; }
#pragma unroll
        for (int r = 0; r < 16; r++) { float p = exp2f(s1[r] - mnew); s1[r] = p; ps += p; }
        ps += __shfl_xor(ps, 32);
        if (__any(mnew > mrow)) {
          float corr = exp2f(mrow - mnew);
          lrow = lrow * corr + ps;
          mrow = mnew;
#pragma unroll
          for (int r = 0; r < 16; r++) { o0[r] *= corr; o1[r] *= corr; }
        } else {
          lrow += ps;
        }

        s16x8 bf0, bf1, bf2, bf3;
#define MK_BFRAG(dst, tile, base)                                          \
        {                                                                  \
          unsigned X = pk2(tile[base + 0], tile[base + 1]);                \
          unsigned Y = pk2(tile[base + 2], tile[base + 3]);                \
          unsigned Z = pk2(tile[base + 4], tile[base + 5]);                \
          unsigned Wd = pk2(tile[base + 6], tile[base + 7]);               \
          unsigned Xs = __shfl_xor(X, 32), Ys = __shfl_xor(Y, 32);         \
          unsigned Zs = __shfl_xor(Z, 32), Ws = __shfl_xor(Wd, 32);        \
          u32x4 wq;                                                        \
          wq.x = hi ? Zs : X; wq.y = hi ? Ws : Y;                          \
          wq.z = hi ? Z : Xs; wq.w = hi ? Wd : Ys;                         \
          dst = __builtin_bit_cast(s16x8, wq);                             \
        }
        MK_BFRAG(bf0, s0, 0)
        MK_BFRAG(bf1, s0, 8)
        MK_BFRAG(bf2, s1, 0)
        MK_BFRAG(bf3, s1, 8)
#undef MK_BFRAG

        __builtin_amdgcn_s_setprio(1);
#pragma unroll
        for (int ss = 0; ss < 4; ss++) {
          int sidx = kvh * 8 + ss * 2 + hi;
          s16x8 bfr = (ss == 0) ? bf0 : (ss == 1) ? bf1 : (ss == 2) ? bf2 : bf3;
          int sla = (sidx ^ (ln32 & 15)) * 8;
          s16x8 va = *(const s16x8*)(Vc + ln32 * 128 + sla);
          o0 = __builtin_amdgcn_mfma_f32_32x32x16_bf16(va, bfr, o0, 0, 0, 0);
          int slb = (sidx ^ ((32 + ln32) & 15)) * 8;
          s16x8 vb = *(const s16x8*)(Vc + (32 + ln32) * 128 + slb);
          o1 = __builtin_amdgcn_mfma_f32_32x32x16_bf16(vb, bfr, o1, 0, 0, 0);
        }
        __builtin_amdgcn_s_setprio(0);
      }
    }

    __builtin_amdgcn_sched_barrier(0);
    asm volatile("s_waitcnt lgkmcnt(0)" ::: "memory");
    __builtin_amdgcn_s_barrier();
    cur ^= 1;
  }
#undef STAGEKV

  float linv = 1.0f / lrow;
  int orow = (bh >> 5) * SEQ + qg;
  __hip_bfloat16* ob = attn + (size_t)orow * HID + h * HD;
#pragma unroll
  for (int rp = 0; rp < 16; rp += 2) {
    int d0 = (rp & 3) + 8 * (rp >> 2) + 4 * hi;
    *(unsigned*)(ob + d0)      = pk2(o0[rp] * linv, o0[rp + 1] * linv);
    *(unsigned*)(ob + 32 + d0) = pk2(o1[rp] * linv, o1[rp + 1] * linv);
  }
}

extern "C" void kernel_launch(void* const* d_in, const int* in_sizes, int n_in,
                              void* d_out, int out_size, void* d_ws, size_t ws_size,
                              hipStream_t stream) {
  (void)in_sizes; (void)n_in; (void)out_size; (void)ws_size;
  const float* hid = (const float*)d_in[0];
  const float* Wq  = (const float*)d_in[1];
  const float* Wk  = (const float*)d_in[2];
  const float* Wv  = (const float*)d_in[3];
  const float* Wo  = (const float*)d_in[4];
  const float* bo  = (const float*)d_in[5];

  char* ws = (char*)d_ws;
  size_t off = 0;
  __hip_bfloat16* hidB = (__hip_bfloat16*)(ws + off); off += (size_t)ROWS * HID * 2;
  __hip_bfloat16* WqB  = (__hip_bfloat16*)(ws + off); off += (size_t)HID * HID * 2;
  __hip_bfloat16* WkB  = (__hip_bfloat16*)(ws + off); off += (size_t)HID * HID * 2;
  __hip_bfloat16* WvB  = (__hip_bfloat16*)(ws + off); off += (size_t)HID * HID * 2;
  __hip_bfloat16* WoB  = (__hip_bfloat16*)(ws + off); off += (size_t)HID * HID * 2;
  __hip_bfloat16* Qr   = (__hip_bfloat16*)(ws + off); off += (size_t)ROWS * HID * 2;
  __hip_bfloat16* Kr   = (__hip_bfloat16*)(ws + off); off += (size_t)ROWS * HID * 2;
  __hip_bfloat16* vlin = (__hip_bfloat16*)(ws + off); off += (size_t)ROWS * HID * 2;
  __hip_bfloat16* Vt   = hidB;       // alias: hidden bf16 dead after QKV GEMMs
  __hip_bfloat16* attn = vlin;       // alias: vlin dead after transpose_v

  castk<<<(ROWS * HID / 8 + 255) / 256, 256, 0, stream>>>(hid, hidB, ROWS * HID / 8);
  castk<<<(HID * HID / 8 + 255) / 256, 256, 0, stream>>>(Wq, WqB, HID * HID / 8);
  castk<<<(HID * HID / 8 + 255) / 256, 256, 0, stream>>>(Wk, WkB, HID * HID / 8);
  castk<<<(HID * HID / 8 + 255) / 256, 256, 0, stream>>>(Wv, WvB, HID * HID / 8);
  castk<<<(HID * HID / 8 + 255) / 256, 256, 0, stream>>>(Wo, WoB, HID * HID / 8);

  dim3 gg(HID / 256, ROWS / 256);   // 8 x 32 = 256 blocks
  gemm256<1><<<gg, 512, 0, stream>>>(hidB, WqB, nullptr, (void*)Qr);
  gemm256<2><<<gg, 512, 0, stream>>>(hidB, WkB, nullptr, (void*)Kr);
  gemm256<0><<<gg, 512, 0, stream>>>(hidB, WvB, nullptr, (void*)vlin);

  transpose_v<<<BATCH * NH * (SEQ / 64), 256, 0, stream>>>(vlin, Vt);

  flash<<<BATCH * NH * (SEQ / 256), 512, 0, stream>>>(Qr, Kr, Vt, attn);

  gemm256<3><<<gg, 512, 0, stream>>>(attn, WoB, bo, d_out);
}

// Round 5
// 580.459 us; speedup vs baseline: 1.4474x; 1.1269x over previous
//
#include <hip/hip_runtime.h>
#include <hip/hip_bf16.h>
#include <stdint.h>

#define HID 2048
#define SEQ 4096
#define BATCH 2
#define NH 32
#define HD 64
#define ROWS (BATCH*SEQ)
#define LOCAL_H 30
#define LOG2E 1.4426950408889634f
#define NT 32              // K tiles of 64 in 2048

typedef __attribute__((ext_vector_type(4))) float f32x4;
typedef __attribute__((ext_vector_type(16))) float f32x16;
typedef __attribute__((ext_vector_type(8))) short s16x8;
typedef __attribute__((ext_vector_type(4))) unsigned int u32x4;

__device__ __forceinline__ void g2l16(const void* g, void* l) {
  __builtin_amdgcn_global_load_lds((__attribute__((address_space(1))) void*)(g),
                                   (__attribute__((address_space(3))) void*)(l), 16, 0, 0);
}

__device__ __forceinline__ unsigned pk2(float a, float b) {
  union { __hip_bfloat16 h; unsigned short u; } x, y;
  x.h = __float2bfloat16(a); y.h = __float2bfloat16(b);
  return ((unsigned)y.u << 16) | x.u;
}

__device__ __forceinline__ unsigned cvtpk(float lo, float hi) {
  unsigned d;
  asm("v_cvt_pk_bf16_f32 %0, %1, %2" : "=v"(d) : "v"(lo), "v"(hi));
  return d;
}

__device__ __forceinline__ void pl32swap(unsigned &a, unsigned &b) {
  asm volatile("v_permlane32_swap_b32 %0, %1" : "+v"(a), "+v"(b));
}

// segment decode tables (flash) and combine tables
__device__ const unsigned char Gq40[40] = {0,1,2,3, 4,4,5,5,6,6,7,7,
  8,8,8,9,9,9,10,10,10,11,11,11, 12,12,12,12,13,13,13,13,14,14,14,14,15,15,15,15};
__device__ const unsigned char Gs40[40] = {0,0,0,0, 0,1,0,1,0,1,0,1,
  0,1,2,0,1,2,0,1,2,0,1,2, 0,1,2,3,0,1,2,3,0,1,2,3,0,1,2,3};
__device__ const unsigned char PG16[16] = {0,0,0,0, 0,2,4,6, 8,11,14,17, 20,24,28,32};
__device__ const unsigned char Lq22[22] = {6,6,7,7,10,10,11,11,14,14,15,15, 0,1,2,3,4,5,8,9,12,13};
__device__ const unsigned char Ls22[22] = {0,1,0,1,0,1,0,1,0,1,0,1, 0,0,0,0,0,0,0,0,0,0};
__device__ const unsigned char QT6[6]   = {6,7,10,11,14,15};
__device__ const unsigned char PG12[12] = {0,2,4,6,8,11,14,17,20,24,28,32};

// ---------------- cast f32 -> bf16 ----------------
__global__ __launch_bounds__(256) void castk(const float* __restrict__ s,
                                             __hip_bfloat16* __restrict__ d, int n8) {
  int i = blockIdx.x * 256 + threadIdx.x;
  if (i >= n8) return;
  const f32x4* sp = (const f32x4*)(s) + (size_t)i * 2;
  f32x4 a = sp[0], b = sp[1];
  __hip_bfloat16 t[8];
#pragma unroll
  for (int j = 0; j < 4; j++) { t[j] = __float2bfloat16(a[j]); t[j+4] = __float2bfloat16(b[j]); }
  *(s16x8*)(d + (size_t)i * 8) = *(const s16x8*)t;
}

// ---------------- 256x256 deep-pipelined NT GEMM (unchanged from R4) ----------------
template<int MODE>
__global__ __launch_bounds__(512) void gemm256(const __hip_bfloat16* __restrict__ A,
                                               const __hip_bfloat16* __restrict__ W,
                                               const float* __restrict__ bias,
                                               void* __restrict__ outp) {
  __shared__ __hip_bfloat16 lds[2][4][128 * 64];
  const int tid = threadIdx.x;
  const int lane = tid & 63, wv = tid >> 6;
  const int wm = wv >> 2, wn = wv & 3;
  const int g = lane >> 4, ln = lane & 15;
  const int m0 = blockIdx.y * 256, n0 = blockIdx.x * 256;

  const int srow = tid >> 3, sslot = tid & 7;
  const int scolE = (sslot ^ (srow & 7)) * 8;
  const int srow2 = (512 + tid) >> 3;
  const int scolE2 = (sslot ^ (srow2 & 7)) * 8;

#define STAGE(srcbase, ldK, kt, region)                                         \
  {                                                                             \
    g2l16((srcbase) + (size_t)(srow) * (ldK) + (kt) + scolE,                    \
          (void*)(&lds[0][0][0] + (region) * 8192 + wv * 512));                 \
    g2l16((srcbase) + (size_t)(srow2) * (ldK) + (kt) + scolE2,                  \
          (void*)(&lds[0][0][0] + (region) * 8192 + 4096 + wv * 512));          \
  }

  f32x4 acc[8][4];
#pragma unroll
  for (int i = 0; i < 8; i++)
#pragma unroll
    for (int j = 0; j < 4; j++) acc[i][j] = (f32x4)0.f;

  STAGE(A + (size_t)m0 * HID,           HID, 0, 0);
  STAGE(W + (size_t)n0 * HID,           HID, 0, 2);
  STAGE(W + (size_t)(n0 + 128) * HID,   HID, 0, 3);
  STAGE(A + (size_t)(m0 + 128) * HID,   HID, 0, 1);

  for (int t = 0; t < NT; ++t) {
    const int buf = t & 1, nbuf = buf ^ 1;
    const int ktn = (t + 1) * 64;
    const bool pre = (t + 1 < NT);
#pragma unroll
    for (int p = 0; p < 4; ++p) {
      if (pre) {
        if (p == 0) STAGE(A + (size_t)m0 * HID,         HID, ktn, nbuf * 4 + 0)
        if (p == 1) STAGE(W + (size_t)n0 * HID,         HID, ktn, nbuf * 4 + 2)
        if (p == 2) STAGE(W + (size_t)(n0 + 128) * HID, HID, ktn, nbuf * 4 + 3)
        if (p == 3) STAGE(A + (size_t)(m0 + 128) * HID, HID, ktn, nbuf * 4 + 1)
        asm volatile("s_waitcnt vmcnt(4)" ::: "memory");
      } else if (p == 0) {
        asm volatile("s_waitcnt vmcnt(0)" ::: "memory");
      }
      __builtin_amdgcn_sched_barrier(0);
      __builtin_amdgcn_s_barrier();
      __builtin_amdgcn_sched_barrier(0);

      const int mi = p >> 1, ni = p & 1;
      const __hip_bfloat16* Ah = &lds[buf][mi][0];
      const __hip_bfloat16* Bh = &lds[buf][2 + (wn >> 1)][0];
      s16x8 af[4][2], bfv[2][2];
#pragma unroll
      for (int st = 0; st < 4; st++) {
        int row = wm * 64 + st * 16 + ln;
#pragma unroll
        for (int ks = 0; ks < 2; ks++)
          af[st][ks] = *(const s16x8*)(Ah + row * 64 + (((ks * 4 + g) ^ (row & 7)) * 8));
      }
#pragma unroll
      for (int st2 = 0; st2 < 2; st2++) {
        int row = (wn & 1) * 64 + ni * 32 + st2 * 16 + ln;
#pragma unroll
        for (int ks = 0; ks < 2; ks++)
          bfv[st2][ks] = *(const s16x8*)(Bh + row * 64 + (((ks * 4 + g) ^ (row & 7)) * 8));
      }
      __builtin_amdgcn_s_setprio(1);
#pragma unroll
      for (int st = 0; st < 4; st++)
#pragma unroll
        for (int st2 = 0; st2 < 2; st2++)
#pragma unroll
          for (int ks = 0; ks < 2; ks++)
            acc[mi * 4 + st][ni * 2 + st2] =
              __builtin_amdgcn_mfma_f32_16x16x32_bf16(af[st][ks], bfv[st2][ks],
                                                      acc[mi * 4 + st][ni * 2 + st2], 0, 0, 0);
      __builtin_amdgcn_s_setprio(0);
    }
  }
#undef STAGE

  const int n0c = n0 + (wn >> 1) * 128 + (wn & 1) * 64;
#pragma unroll
  for (int am = 0; am < 8; am++) {
#pragma unroll
    for (int r = 0; r < 4; r++) {
      int grow = m0 + (am >> 2) * 128 + wm * 64 + (am & 3) * 16 + g * 4 + r;
      if constexpr (MODE == 0) {
        __hip_bfloat16* o = (__hip_bfloat16*)outp + (size_t)grow * HID + n0c;
#pragma unroll
        for (int j = 0; j < 4; j++) o[j * 16 + ln] = __float2bfloat16(acc[am][j][r]);
      } else if constexpr (MODE == 3) {
        float* o = (float*)outp + (size_t)grow * HID + n0c;
#pragma unroll
        for (int j = 0; j < 4; j++)
          o[j * 16 + ln] = acc[am][j][r] + bias[n0c + j * 16 + ln];
      } else {
        int b = grow >> 12, l = grow & (SEQ - 1);
        int h = n0c >> 6;
        __hip_bfloat16* o = (__hip_bfloat16*)outp + ((size_t)(b * NH + h) * SEQ + l) * HD;
#pragma unroll
        for (int j = 0; j < 2; j++) {
          int d = j * 16 + ln;
          float x1 = acc[am][j][r], x2 = acc[am][j + 2][r];
          float ang = (float)l * exp2f((float)d * -0.41524101186091903f);
          float sn, cs;
          sincosf(ang, &sn, &cs);
          float o1 = x1 * cs - x2 * sn;
          float o2 = x2 * cs + x1 * sn;
          if constexpr (MODE == 1) { o1 *= 0.125f * LOG2E; o2 *= 0.125f * LOG2E; }
          o[d]      = __float2bfloat16(o1);
          o[d + 32] = __float2bfloat16(o2);
        }
      }
    }
  }
}

// ---------------- V transpose ----------------
__global__ __launch_bounds__(256) void transpose_v(const __hip_bfloat16* __restrict__ vlin,
                                                   __hip_bfloat16* __restrict__ vt) {
  __shared__ __hip_bfloat16 T[64][72];
  int blk = blockIdx.x;
  int l0 = (blk & 63) * 64;
  int bh = blk >> 6;
  int tid = threadIdx.x;
  {
    int l = tid >> 2, dq = (tid & 3) * 16;
    const __hip_bfloat16* src = vlin + (size_t)((bh >> 5) * SEQ + l0 + l) * HID + (bh & 31) * HD + dq;
    s16x8 v0 = *(const s16x8*)(src);
    s16x8 v1 = *(const s16x8*)(src + 8);
    *(s16x8*)&T[l][dq] = v0;
    *(s16x8*)&T[l][dq + 8] = v1;
  }
  __syncthreads();
  {
    int d = tid >> 2, lq = (tid & 3) * 16;
    __hip_bfloat16 tmp[16];
#pragma unroll
    for (int e = 0; e < 16; e++) tmp[e] = T[lq + e][d];
    __hip_bfloat16* dst = vt + ((size_t)bh * HD + d) * SEQ + l0 + lq;
    *(s16x8*)dst = *(const s16x8*)tmp;
    *(s16x8*)(dst + 8) = *(const s16x8*)(tmp + 8);
  }
}

// ---------------- flash attention v3: split-KV segments <=1024 keys ----------------
// Q pre-scaled by 0.125*log2e (log2 domain). Q,K: [bh][l][64]; Vt: [bh][64][SEQ]
// 8 waves x 32 q = 256 q/block. 64-key chunks double-buffered (32KB LDS).
// Multi-segment tiles write unnormalized partials (PO bf16, PM/PL f32); combine merges.
__global__ __launch_bounds__(512, 4) void flash(const __hip_bfloat16* __restrict__ Q,
                                                const __hip_bfloat16* __restrict__ Kk,
                                                const __hip_bfloat16* __restrict__ Vt,
                                                __hip_bfloat16* __restrict__ attn,
                                                __hip_bfloat16* __restrict__ PO,
                                                float* __restrict__ PM,
                                                float* __restrict__ PL) {
  __shared__ __hip_bfloat16 Ks[2][64 * 64];
  __shared__ __hip_bfloat16 Vs[2][64 * 64];

  int bi = blockIdx.x;
  int b, h, qtl, seg, pidx;
  if (bi < 160) {                      // global heads (longest, dispatched first)
    int gidx = bi / 40, r = bi % 40;
    qtl = Gq40[r]; seg = Gs40[r];
    int nseg = (qtl >> 2) + 1;
    b = gidx >> 1; h = 30 + (gidx & 1);
    pidx = (nseg > 1) ? (720 + gidx * 36 + PG16[qtl] + seg) : -1;
  } else {
    int li = bi - 160;
    int lidx = li / 22, r = li % 22;
    qtl = Lq22[r]; seg = Ls22[r];
    b = lidx / 30; h = lidx % 30;
    pidx = (r < 12) ? (lidx * 12 + r) : -1;
  }
  const int bhid = b * NH + h;
  const int q0 = qtl * 256;
  int ks0t = 0;
  if (h < LOCAL_H) { int gq = qtl >> 2; ks0t = gq ? gq * 1024 - 512 : 0; }
  const int kstart = ks0t + seg * 1024;
  const int kend_t = q0 + 256;
  const int kend_s = (kend_t < kstart + 1024) ? kend_t : kstart + 1024;
  const int nch = (kend_s - kstart) >> 6;

  const int tid = threadIdx.x, lane = tid & 63, wv = tid >> 6;
  const int ln32 = lane & 31, hi = lane >> 5;
  const int qw0 = q0 + wv * 32;
  const int qg = qw0 + ln32;

  const __hip_bfloat16* qb = Q + ((size_t)bhid * SEQ + qg) * HD + hi * 8;
  s16x8 qf[4];
#pragma unroll
  for (int tt = 0; tt < 4; tt++) qf[tt] = *(const s16x8*)(qb + tt * 16);

  float mrow = -3.0e38f, lrow = 0.f;
  f32x16 o0 = (f32x16)0.f, o1 = (f32x16)0.f;

  // staging: thread stages chunk tid (1 K + 1 V 16B-load); swizzle S = slot^(row&7)^((row>>1)&4)
  const int srow = tid >> 3, sslot = tid & 7;
  const int scolE = (sslot ^ (srow & 7) ^ ((srow >> 1) & 4)) * 8;
  // read-side xor (rows ln32 and 32+ln32 share it)
  const int sxor = (ln32 & 7) ^ ((ln32 >> 1) & 4);

#define STAGEKV(bb, kc)                                                                   \
  {                                                                                       \
    g2l16(Kk + ((size_t)bhid * SEQ + (kc) + srow) * HD + scolE, (void*)(&Ks[bb][0] + wv * 512)); \
    g2l16(Vt + ((size_t)bhid * HD + srow) * SEQ + (kc) + scolE, (void*)(&Vs[bb][0] + wv * 512)); \
  }

  STAGEKV(0, kstart)

  int cur = 0;
  for (int ci = 0; ci < nch; ci++) {
    int kc = kstart + ci * 64;
    if (ci + 1 < nch) {
      STAGEKV(cur ^ 1, kc + 64)
      asm volatile("s_waitcnt vmcnt(2)" ::: "memory");
    } else {
      asm volatile("s_waitcnt vmcnt(0)" ::: "memory");
    }
    __builtin_amdgcn_s_barrier();
    __builtin_amdgcn_sched_barrier(0);

    if (kc <= qw0 + 31) {            // wave-uniform skip of fully-masked chunks
      const __hip_bfloat16* Kc = &Ks[cur][0];
      const __hip_bfloat16* Vc = &Vs[cur][0];

      f32x16 s0 = (f32x16)0.f, s1 = (f32x16)0.f;
      __builtin_amdgcn_s_setprio(1);
#pragma unroll
      for (int tt = 0; tt < 4; tt++) {
        int sl = ((2 * tt + hi) ^ sxor) * 8;
        s16x8 ka = *(const s16x8*)(Kc + ln32 * 64 + sl);
        s0 = __builtin_amdgcn_mfma_f32_32x32x16_bf16(ka, qf[tt], s0, 0, 0, 0);
        s16x8 kb = *(const s16x8*)(Kc + (32 + ln32) * 64 + sl);
        s1 = __builtin_amdgcn_mfma_f32_32x32x16_bf16(kb, qf[tt], s1, 0, 0, 0);
      }
      __builtin_amdgcn_s_setprio(0);

      if (kc + 63 > qw0) {           // diagonal region: mask kv > q
#pragma unroll
        for (int r = 0; r < 16; r++) {
          int kv0 = kc + (r & 3) + 8 * (r >> 2) + 4 * hi;
          if (kv0 > qg) s0[r] = -1.0e30f;
          if (kv0 + 32 > qg) s1[r] = -1.0e30f;
        }
      }

      // per-lane online softmax (log2 domain), defer-max (T13, thr=8)
      float pm = fmaxf(s0[0], s1[0]);
#pragma unroll
      for (int r = 1; r < 16; r++) pm = fmaxf(pm, fmaxf(s0[r], s1[r]));
      pm = fmaxf(pm, __shfl_xor(pm, 32));
      bool resc = !__all(pm <= mrow + 8.0f);
      float mu = resc ? fmaxf(mrow, pm) : mrow;
      float ps = 0.f;
#pragma unroll
      for (int r = 0; r < 16; r++) { float p = exp2f(s0[r] - mu); s0[r] = p; ps += p; }
#pragma unroll
      for (int r = 0; r < 16; r++) { float p = exp2f(s1[r] - mu); s1[r] = p; ps += p; }
      ps += __shfl_xor(ps, 32);
      if (resc) {
        float corr = exp2f(mrow - mu);
        lrow = lrow * corr + ps;
        mrow = mu;
#pragma unroll
        for (int r = 0; r < 16; r++) { o0[r] *= corr; o1[r] *= corr; }
      } else {
        lrow += ps;
      }

      // P^T B-fragments in-register: cvt_pk + permlane32_swap (T12)
      s16x8 pfr[4];
#pragma unroll
      for (int fb = 0; fb < 4; fb++) {
        const f32x16& tile = (fb < 2) ? s0 : s1;
        const int base = (fb & 1) * 8;
        unsigned X = cvtpk(tile[base + 0], tile[base + 1]);
        unsigned Y = cvtpk(tile[base + 2], tile[base + 3]);
        unsigned Z = cvtpk(tile[base + 4], tile[base + 5]);
        unsigned Wd = cvtpk(tile[base + 6], tile[base + 7]);
        pl32swap(X, Z);
        pl32swap(Y, Wd);
        u32x4 wq; wq.x = X; wq.y = Y; wq.z = Z; wq.w = Wd;
        pfr[fb] = __builtin_bit_cast(s16x8, wq);
      }

      // O^T += V^T * P
      __builtin_amdgcn_s_setprio(1);
#pragma unroll
      for (int ss = 0; ss < 4; ss++) {
        int sl = ((2 * ss + hi) ^ sxor) * 8;
        s16x8 va = *(const s16x8*)(Vc + ln32 * 64 + sl);
        o0 = __builtin_amdgcn_mfma_f32_32x32x16_bf16(va, pfr[ss], o0, 0, 0, 0);
        s16x8 vb = *(const s16x8*)(Vc + (32 + ln32) * 64 + sl);
        o1 = __builtin_amdgcn_mfma_f32_32x32x16_bf16(vb, pfr[ss], o1, 0, 0, 0);
      }
      __builtin_amdgcn_s_setprio(0);
    }

    __builtin_amdgcn_sched_barrier(0);
    asm volatile("s_waitcnt lgkmcnt(0)" ::: "memory");
    __builtin_amdgcn_s_barrier();
    cur ^= 1;
  }
#undef STAGEKV

  if (pidx < 0) {
    float linv = 1.0f / lrow;
    int orow = b * SEQ + qg;
    __hip_bfloat16* ob = attn + (size_t)orow * HID + h * HD;
#pragma unroll
    for (int rp = 0; rp < 16; rp += 2) {
      int d0 = (rp & 3) + 8 * (rp >> 2) + 4 * hi;
      *(unsigned*)(ob + d0)      = pk2(o0[rp] * linv, o0[rp + 1] * linv);
      *(unsigned*)(ob + 32 + d0) = pk2(o1[rp] * linv, o1[rp + 1] * linv);
    }
  } else {
    int tq = wv * 32 + ln32;
    __hip_bfloat16* pob = PO + ((size_t)pidx * 256 + tq) * 64;
#pragma unroll
    for (int rp = 0; rp < 16; rp += 2) {
      int d0 = (rp & 3) + 8 * (rp >> 2) + 4 * hi;
      *(unsigned*)(pob + d0)      = pk2(o0[rp], o0[rp + 1]);
      *(unsigned*)(pob + 32 + d0) = pk2(o1[rp], o1[rp + 1]);
    }
    if (hi == 0) {
      PM[pidx * 256 + tq] = mrow;
      PL[pidx * 256 + tq] = lrow;
    }
  }
}

// ---------------- combine partials ----------------
__global__ __launch_bounds__(256) void combine(const __hip_bfloat16* __restrict__ PO,
                                               const float* __restrict__ PM,
                                               const float* __restrict__ PL,
                                               __hip_bfloat16* __restrict__ attn) {
  int bi = blockIdx.x;
  int b, h, qtl, ns, pbase;
  if (bi < 360) {
    int lidx = bi / 6, j2 = bi % 6;
    qtl = QT6[j2]; ns = 2; pbase = lidx * 12 + j2 * 2;
    b = lidx / 30; h = lidx % 30;
  } else {
    int gi = bi - 360;
    int gidx = gi / 12, j2 = gi % 12;
    qtl = 4 + j2; ns = (qtl >> 2) + 1;
    pbase = 720 + gidx * 36 + PG12[j2];
    b = gidx >> 1; h = 30 + (gidx & 1);
  }
  int tq = threadIdx.x;
  float m = -3.0e38f;
  for (int s = 0; s < ns; s++) m = fmaxf(m, PM[(pbase + s) * 256 + tq]);
  float wsum = 0.f;
  float oacc[64];
#pragma unroll
  for (int d = 0; d < 64; d++) oacc[d] = 0.f;
  for (int s = 0; s < ns; s++) {
    float w = exp2f(PM[(pbase + s) * 256 + tq] - m);
    wsum += w * PL[(pbase + s) * 256 + tq];
    const s16x8* po = (const s16x8*)(PO + ((size_t)(pbase + s) * 256 + tq) * 64);
#pragma unroll
    for (int u = 0; u < 8; u++) {
      s16x8 v = po[u];
#pragma unroll
      for (int e = 0; e < 8; e++) {
        union { unsigned uu; float f; } cv;
        cv.uu = ((unsigned)(unsigned short)v[e]) << 16;
        oacc[u * 8 + e] += w * cv.f;
      }
    }
  }
  float inv = 1.0f / wsum;
  __hip_bfloat16* ob = attn + ((size_t)(b * SEQ + qtl * 256 + tq)) * HID + h * HD;
#pragma unroll
  for (int d = 0; d < 64; d += 2)
    *(unsigned*)(ob + d) = pk2(oacc[d] * inv, oacc[d + 1] * inv);
}

extern "C" void kernel_launch(void* const* d_in, const int* in_sizes, int n_in,
                              void* d_out, int out_size, void* d_ws, size_t ws_size,
                              hipStream_t stream) {
  (void)in_sizes; (void)n_in; (void)out_size; (void)ws_size;
  const float* hid = (const float*)d_in[0];
  const float* Wq  = (const float*)d_in[1];
  const float* Wk  = (const float*)d_in[2];
  const float* Wv  = (const float*)d_in[3];
  const float* Wo  = (const float*)d_in[4];
  const float* bo  = (const float*)d_in[5];

  char* ws = (char*)d_ws;
  size_t off = 0;
  __hip_bfloat16* hidB = (__hip_bfloat16*)(ws + off); off += (size_t)ROWS * HID * 2;
  __hip_bfloat16* WqB  = (__hip_bfloat16*)(ws + off); off += (size_t)HID * HID * 2;
  __hip_bfloat16* WkB  = (__hip_bfloat16*)(ws + off); off += (size_t)HID * HID * 2;
  __hip_bfloat16* WvB  = (__hip_bfloat16*)(ws + off); off += (size_t)HID * HID * 2;
  __hip_bfloat16* WoB  = (__hip_bfloat16*)(ws + off); off += (size_t)HID * HID * 2;
  __hip_bfloat16* Qr   = (__hip_bfloat16*)(ws + off); off += (size_t)ROWS * HID * 2;
  __hip_bfloat16* Kr   = (__hip_bfloat16*)(ws + off); off += (size_t)ROWS * HID * 2;
  __hip_bfloat16* vlin = (__hip_bfloat16*)(ws + off); off += (size_t)ROWS * HID * 2;
  __hip_bfloat16* PO   = (__hip_bfloat16*)(ws + off); off += (size_t)864 * 256 * 64 * 2;
  float* PM            = (float*)(ws + off);          off += (size_t)864 * 256 * 4;
  float* PL            = (float*)(ws + off);          off += (size_t)864 * 256 * 4;
  __hip_bfloat16* Vt   = hidB;       // alias: hidden bf16 dead after QKV GEMMs
  __hip_bfloat16* attn = vlin;       // alias: vlin dead after transpose_v

  castk<<<(ROWS * HID / 8 + 255) / 256, 256, 0, stream>>>(hid, hidB, ROWS * HID / 8);
  castk<<<(HID * HID / 8 + 255) / 256, 256, 0, stream>>>(Wq, WqB, HID * HID / 8);
  castk<<<(HID * HID / 8 + 255) / 256, 256, 0, stream>>>(Wk, WkB, HID * HID / 8);
  castk<<<(HID * HID / 8 + 255) / 256, 256, 0, stream>>>(Wv, WvB, HID * HID / 8);
  castk<<<(HID * HID / 8 + 255) / 256, 256, 0, stream>>>(Wo, WoB, HID * HID / 8);

  dim3 gg(HID / 256, ROWS / 256);   // 8 x 32 = 256 blocks
  gemm256<1><<<gg, 512, 0, stream>>>(hidB, WqB, nullptr, (void*)Qr);
  gemm256<2><<<gg, 512, 0, stream>>>(hidB, WkB, nullptr, (void*)Kr);
  gemm256<0><<<gg, 512, 0, stream>>>(hidB, WvB, nullptr, (void*)vlin);

  transpose_v<<<BATCH * NH * (SEQ / 64), 256, 0, stream>>>(vlin, Vt);

  flash<<<1480, 512, 0, stream>>>(Qr, Kr, Vt, attn, PO, PM, PL);
  combine<<<408, 256, 0, stream>>>(PO, PM, PL, attn);

  gemm256<3><<<gg, 512, 0, stream>>>(attn, WoB, bo, d_out);
}

// Round 6
// 573.336 us; speedup vs baseline: 1.4654x; 1.0124x over previous
//
#include <hip/hip_runtime.h>
#include <hip/hip_bf16.h>
#include <stdint.h>

#define HID 2048
#define SEQ 4096
#define BATCH 2
#define NH 32
#define HD 64
#define ROWS (BATCH*SEQ)
#define LOCAL_H 30
#define LOG2E 1.4426950408889634f
#define NT 32              // K tiles of 64 in 2048

typedef __attribute__((ext_vector_type(4))) float f32x4;
typedef __attribute__((ext_vector_type(16))) float f32x16;
typedef __attribute__((ext_vector_type(8))) short s16x8;
typedef __attribute__((ext_vector_type(4))) unsigned int u32x4;

__device__ __forceinline__ void g2l16(const void* g, void* l) {
  __builtin_amdgcn_global_load_lds((__attribute__((address_space(1))) void*)(g),
                                   (__attribute__((address_space(3))) void*)(l), 16, 0, 0);
}

__device__ __forceinline__ unsigned pk2(float a, float b) {
  union { __hip_bfloat16 h; unsigned short u; } x, y;
  x.h = __float2bfloat16(a); y.h = __float2bfloat16(b);
  return ((unsigned)y.u << 16) | x.u;
}

__device__ __forceinline__ unsigned cvtpk(float lo, float hi) {
  unsigned d;
  asm("v_cvt_pk_bf16_f32 %0, %1, %2" : "=v"(d) : "v"(lo), "v"(hi));
  return d;
}

__device__ __forceinline__ void pl32swap(unsigned &a, unsigned &b) {
  asm volatile("v_permlane32_swap_b32 %0, %1" : "+v"(a), "+v"(b));
}

// segment decode tables (flash) and combine tables
__device__ const unsigned char Gq40[40] = {0,1,2,3, 4,4,5,5,6,6,7,7,
  8,8,8,9,9,9,10,10,10,11,11,11, 12,12,12,12,13,13,13,13,14,14,14,14,15,15,15,15};
__device__ const unsigned char Gs40[40] = {0,0,0,0, 0,1,0,1,0,1,0,1,
  0,1,2,0,1,2,0,1,2,0,1,2, 0,1,2,3,0,1,2,3,0,1,2,3,0,1,2,3};
__device__ const unsigned char PG16[16] = {0,0,0,0, 0,2,4,6, 8,11,14,17, 20,24,28,32};
__device__ const unsigned char Lq22[22] = {6,6,7,7,10,10,11,11,14,14,15,15, 0,1,2,3,4,5,8,9,12,13};
__device__ const unsigned char Ls22[22] = {0,1,0,1,0,1,0,1,0,1,0,1, 0,0,0,0,0,0,0,0,0,0};
__device__ const unsigned char QT6[6]   = {6,7,10,11,14,15};
__device__ const unsigned char PG12[12] = {0,2,4,6,8,11,14,17,20,24,28,32};

// ---------------- cast f32 -> bf16 ----------------
__global__ __launch_bounds__(256) void castk(const float* __restrict__ s,
                                             __hip_bfloat16* __restrict__ d, int n8) {
  int i = blockIdx.x * 256 + threadIdx.x;
  if (i >= n8) return;
  const f32x4* sp = (const f32x4*)(s) + (size_t)i * 2;
  f32x4 a = sp[0], b = sp[1];
  __hip_bfloat16 t[8];
#pragma unroll
  for (int j = 0; j < 4; j++) { t[j] = __float2bfloat16(a[j]); t[j+4] = __float2bfloat16(b[j]); }
  *(s16x8*)(d + (size_t)i * 8) = *(const s16x8*)t;
}

// cast 4 weights (dsts contiguous at dbase + y*HID*HID)
__global__ __launch_bounds__(256) void castw(const float* __restrict__ w0,
                                             const float* __restrict__ w1,
                                             const float* __restrict__ w2,
                                             const float* __restrict__ w3,
                                             __hip_bfloat16* __restrict__ dbase) {
  const float* s = (blockIdx.y == 0) ? w0 : (blockIdx.y == 1) ? w1 : (blockIdx.y == 2) ? w2 : w3;
  __hip_bfloat16* d = dbase + (size_t)blockIdx.y * HID * HID;
  int i = blockIdx.x * 256 + threadIdx.x;
  const f32x4* sp = (const f32x4*)(s) + (size_t)i * 2;
  f32x4 a = sp[0], b = sp[1];
  __hip_bfloat16 t[8];
#pragma unroll
  for (int j = 0; j < 4; j++) { t[j] = __float2bfloat16(a[j]); t[j+4] = __float2bfloat16(b[j]); }
  *(s16x8*)(d + (size_t)i * 8) = *(const s16x8*)t;
}

// ---------------- 256x256 deep-pipelined NT GEMM, T3/T4 schedule ----------------
// C[M][N] = A[M][K] * W[N][K]^T. 8 waves (2M x 4N); wave tile 128x64.
// Per K-tile: 2 blocks (mi=0/1), each {STAGE, counted vmcnt, barrier, ds_read, 32 MFMA}.
// Stage order A0,B0,B1,A1; vmcnt(4) at block0, vmcnt(6) at block1 (derivation in notes).
template<int MODE>
__global__ __launch_bounds__(512) void gemm256(const __hip_bfloat16* __restrict__ A,
                                               const __hip_bfloat16* __restrict__ W,
                                               const float* __restrict__ bias,
                                               void* __restrict__ outp) {
  __shared__ __hip_bfloat16 lds[2][4][128 * 64];   // [buf][A0,A1,B0,B1]
  const int tid = threadIdx.x;
  const int lane = tid & 63, wv = tid >> 6;
  const int wm = wv >> 2, wn = wv & 3;
  const int g = lane >> 4, ln = lane & 15;
  const int m0 = blockIdx.y * 256, n0 = blockIdx.x * 256;

  const int srow = tid >> 3, sslot = tid & 7;
  const int scolE = (sslot ^ (srow & 7)) * 8;
  const int srow2 = (512 + tid) >> 3;
  const int scolE2 = (sslot ^ (srow2 & 7)) * 8;

#define STAGE(srcbase, ldK, kt, region)                                         \
  {                                                                             \
    g2l16((srcbase) + (size_t)(srow) * (ldK) + (kt) + scolE,                    \
          (void*)(&lds[0][0][0] + (region) * 8192 + wv * 512));                 \
    g2l16((srcbase) + (size_t)(srow2) * (ldK) + (kt) + scolE2,                  \
          (void*)(&lds[0][0][0] + (region) * 8192 + 4096 + wv * 512));          \
  }

  f32x4 acc[8][4];
#pragma unroll
  for (int i = 0; i < 8; i++)
#pragma unroll
    for (int j = 0; j < 4; j++) acc[i][j] = (f32x4)0.f;

  // prologue: tile 0 into buf 0, order A0,B0,B1,A1
  STAGE(A + (size_t)m0 * HID,           HID, 0, 0);
  STAGE(W + (size_t)n0 * HID,           HID, 0, 2);
  STAGE(W + (size_t)(n0 + 128) * HID,   HID, 0, 3);
  STAGE(A + (size_t)(m0 + 128) * HID,   HID, 0, 1);

  for (int t = 0; t < NT; ++t) {
    const int buf = t & 1, nbuf = buf ^ 1;
    const int ktn = (t + 1) * 64;
    const bool pre = (t + 1 < NT);
    const __hip_bfloat16* Bh = &lds[buf][2 + (wn >> 1)][0];

#pragma unroll
    for (int mi = 0; mi < 2; mi++) {
      // block entry: stage next-tile half, counted wait, barrier
      if (pre) {
        if (mi == 0) { STAGE(A + (size_t)m0 * HID,         HID, ktn, nbuf * 4 + 0) }  // A0'
        else         { STAGE(W + (size_t)(n0 + 128) * HID, HID, ktn, nbuf * 4 + 3) }  // B1'
      }
      if (pre) {
        if (mi == 0) { asm volatile("s_waitcnt vmcnt(4)" ::: "memory"); }
        else         { asm volatile("s_waitcnt vmcnt(6)" ::: "memory"); }
      } else if (mi == 0) {
        asm volatile("s_waitcnt vmcnt(0)" ::: "memory");
      }
      __builtin_amdgcn_sched_barrier(0);
      __builtin_amdgcn_s_barrier();
      __builtin_amdgcn_sched_barrier(0);

      const __hip_bfloat16* Ah = &lds[buf][mi][0];
      s16x8 af[4][2];
#pragma unroll
      for (int st = 0; st < 4; st++) {
        int row = wm * 64 + st * 16 + ln;
#pragma unroll
        for (int ks = 0; ks < 2; ks++)
          af[st][ks] = *(const s16x8*)(Ah + row * 64 + (((ks * 4 + g) ^ (row & 7)) * 8));
      }
#pragma unroll
      for (int ni = 0; ni < 2; ni++) {
        s16x8 bfv[2][2];
#pragma unroll
        for (int st2 = 0; st2 < 2; st2++) {
          int row = (wn & 1) * 64 + ni * 32 + st2 * 16 + ln;
#pragma unroll
          for (int ks = 0; ks < 2; ks++)
            bfv[st2][ks] = *(const s16x8*)(Bh + row * 64 + (((ks * 4 + g) ^ (row & 7)) * 8));
        }
        if (pre && ni == 1) {
          if (mi == 0) { STAGE(W + (size_t)n0 * HID,         HID, ktn, nbuf * 4 + 2) }  // B0'
          else         { STAGE(A + (size_t)(m0 + 128) * HID, HID, ktn, nbuf * 4 + 1) }  // A1'
        }
        __builtin_amdgcn_s_setprio(1);
#pragma unroll
        for (int st = 0; st < 4; st++)
#pragma unroll
          for (int st2 = 0; st2 < 2; st2++)
#pragma unroll
            for (int ks = 0; ks < 2; ks++)
              acc[mi * 4 + st][ni * 2 + st2] =
                __builtin_amdgcn_mfma_f32_16x16x32_bf16(af[st][ks], bfv[st2][ks],
                                                        acc[mi * 4 + st][ni * 2 + st2], 0, 0, 0);
        __builtin_amdgcn_s_setprio(0);
      }
    }
  }
#undef STAGE

  const int n0c = n0 + (wn >> 1) * 128 + (wn & 1) * 64;
#pragma unroll
  for (int am = 0; am < 8; am++) {
#pragma unroll
    for (int r = 0; r < 4; r++) {
      int grow = m0 + (am >> 2) * 128 + wm * 64 + (am & 3) * 16 + g * 4 + r;
      if constexpr (MODE == 0) {
        __hip_bfloat16* o = (__hip_bfloat16*)outp + (size_t)grow * HID + n0c;
#pragma unroll
        for (int j = 0; j < 4; j++) o[j * 16 + ln] = __float2bfloat16(acc[am][j][r]);
      } else if constexpr (MODE == 3) {
        float* o = (float*)outp + (size_t)grow * HID + n0c;
#pragma unroll
        for (int j = 0; j < 4; j++)
          o[j * 16 + ln] = acc[am][j][r] + bias[n0c + j * 16 + ln];
      } else {
        int b = grow >> 12, l = grow & (SEQ - 1);
        int h = n0c >> 6;
        __hip_bfloat16* o = (__hip_bfloat16*)outp + ((size_t)(b * NH + h) * SEQ + l) * HD;
#pragma unroll
        for (int j = 0; j < 2; j++) {
          int d = j * 16 + ln;
          float x1 = acc[am][j][r], x2 = acc[am][j + 2][r];
          float ang = (float)l * exp2f((float)d * -0.41524101186091903f);
          float sn, cs;
          sincosf(ang, &sn, &cs);
          float o1 = x1 * cs - x2 * sn;
          float o2 = x2 * cs + x1 * sn;
          if constexpr (MODE == 1) { o1 *= 0.125f * LOG2E; o2 *= 0.125f * LOG2E; }
          o[d]      = __float2bfloat16(o1);
          o[d + 32] = __float2bfloat16(o2);
        }
      }
    }
  }
}

// ---------------- V transpose ----------------
__global__ __launch_bounds__(256) void transpose_v(const __hip_bfloat16* __restrict__ vlin,
                                                   __hip_bfloat16* __restrict__ vt) {
  __shared__ __hip_bfloat16 T[64][72];
  int blk = blockIdx.x;
  int l0 = (blk & 63) * 64;
  int bh = blk >> 6;
  int tid = threadIdx.x;
  {
    int l = tid >> 2, dq = (tid & 3) * 16;
    const __hip_bfloat16* src = vlin + (size_t)((bh >> 5) * SEQ + l0 + l) * HID + (bh & 31) * HD + dq;
    s16x8 v0 = *(const s16x8*)(src);
    s16x8 v1 = *(const s16x8*)(src + 8);
    *(s16x8*)&T[l][dq] = v0;
    *(s16x8*)&T[l][dq + 8] = v1;
  }
  __syncthreads();
  {
    int d = tid >> 2, lq = (tid & 3) * 16;
    __hip_bfloat16 tmp[16];
#pragma unroll
    for (int e = 0; e < 16; e++) tmp[e] = T[lq + e][d];
    __hip_bfloat16* dst = vt + ((size_t)bh * HD + d) * SEQ + l0 + lq;
    *(s16x8*)dst = *(const s16x8*)tmp;
    *(s16x8*)(dst + 8) = *(const s16x8*)(tmp + 8);
  }
}

// ---------------- flash attention v3: split-KV segments <=1024 keys (unchanged R5) ----------------
__global__ __launch_bounds__(512, 4) void flash(const __hip_bfloat16* __restrict__ Q,
                                                const __hip_bfloat16* __restrict__ Kk,
                                                const __hip_bfloat16* __restrict__ Vt,
                                                __hip_bfloat16* __restrict__ attn,
                                                __hip_bfloat16* __restrict__ PO,
                                                float* __restrict__ PM,
                                                float* __restrict__ PL) {
  __shared__ __hip_bfloat16 Ks[2][64 * 64];
  __shared__ __hip_bfloat16 Vs[2][64 * 64];

  int bi = blockIdx.x;
  int b, h, qtl, seg, pidx;
  if (bi < 160) {                      // global heads (longest, dispatched first)
    int gidx = bi / 40, r = bi % 40;
    qtl = Gq40[r]; seg = Gs40[r];
    int nseg = (qtl >> 2) + 1;
    b = gidx >> 1; h = 30 + (gidx & 1);
    pidx = (nseg > 1) ? (720 + gidx * 36 + PG16[qtl] + seg) : -1;
  } else {
    int li = bi - 160;
    int lidx = li / 22, r = li % 22;
    qtl = Lq22[r]; seg = Ls22[r];
    b = lidx / 30; h = lidx % 30;
    pidx = (r < 12) ? (lidx * 12 + r) : -1;
  }
  const int bhid = b * NH + h;
  const int q0 = qtl * 256;
  int ks0t = 0;
  if (h < LOCAL_H) { int gq = qtl >> 2; ks0t = gq ? gq * 1024 - 512 : 0; }
  const int kstart = ks0t + seg * 1024;
  const int kend_t = q0 + 256;
  const int kend_s = (kend_t < kstart + 1024) ? kend_t : kstart + 1024;
  const int nch = (kend_s - kstart) >> 6;

  const int tid = threadIdx.x, lane = tid & 63, wv = tid >> 6;
  const int ln32 = lane & 31, hi = lane >> 5;
  const int qw0 = q0 + wv * 32;
  const int qg = qw0 + ln32;

  const __hip_bfloat16* qb = Q + ((size_t)bhid * SEQ + qg) * HD + hi * 8;
  s16x8 qf[4];
#pragma unroll
  for (int tt = 0; tt < 4; tt++) qf[tt] = *(const s16x8*)(qb + tt * 16);

  float mrow = -3.0e38f, lrow = 0.f;
  f32x16 o0 = (f32x16)0.f, o1 = (f32x16)0.f;

  const int srow = tid >> 3, sslot = tid & 7;
  const int scolE = (sslot ^ (srow & 7) ^ ((srow >> 1) & 4)) * 8;
  const int sxor = (ln32 & 7) ^ ((ln32 >> 1) & 4);

#define STAGEKV(bb, kc)                                                                   \
  {                                                                                       \
    g2l16(Kk + ((size_t)bhid * SEQ + (kc) + srow) * HD + scolE, (void*)(&Ks[bb][0] + wv * 512)); \
    g2l16(Vt + ((size_t)bhid * HD + srow) * SEQ + (kc) + scolE, (void*)(&Vs[bb][0] + wv * 512)); \
  }

  STAGEKV(0, kstart)

  int cur = 0;
  for (int ci = 0; ci < nch; ci++) {
    int kc = kstart + ci * 64;
    if (ci + 1 < nch) {
      STAGEKV(cur ^ 1, kc + 64)
      asm volatile("s_waitcnt vmcnt(2)" ::: "memory");
    } else {
      asm volatile("s_waitcnt vmcnt(0)" ::: "memory");
    }
    __builtin_amdgcn_s_barrier();
    __builtin_amdgcn_sched_barrier(0);

    if (kc <= qw0 + 31) {            // wave-uniform skip of fully-masked chunks
      const __hip_bfloat16* Kc = &Ks[cur][0];
      const __hip_bfloat16* Vc = &Vs[cur][0];

      f32x16 s0 = (f32x16)0.f, s1 = (f32x16)0.f;
      __builtin_amdgcn_s_setprio(1);
#pragma unroll
      for (int tt = 0; tt < 4; tt++) {
        int sl = ((2 * tt + hi) ^ sxor) * 8;
        s16x8 ka = *(const s16x8*)(Kc + ln32 * 64 + sl);
        s0 = __builtin_amdgcn_mfma_f32_32x32x16_bf16(ka, qf[tt], s0, 0, 0, 0);
        s16x8 kb = *(const s16x8*)(Kc + (32 + ln32) * 64 + sl);
        s1 = __builtin_amdgcn_mfma_f32_32x32x16_bf16(kb, qf[tt], s1, 0, 0, 0);
      }
      __builtin_amdgcn_s_setprio(0);

      if (kc + 63 > qw0) {           // diagonal region: mask kv > q
#pragma unroll
        for (int r = 0; r < 16; r++) {
          int kv0 = kc + (r & 3) + 8 * (r >> 2) + 4 * hi;
          if (kv0 > qg) s0[r] = -1.0e30f;
          if (kv0 + 32 > qg) s1[r] = -1.0e30f;
        }
      }

      // per-lane online softmax (log2 domain), defer-max (T13, thr=8)
      float pm = fmaxf(s0[0], s1[0]);
#pragma unroll
      for (int r = 1; r < 16; r++) pm = fmaxf(pm, fmaxf(s0[r], s1[r]));
      pm = fmaxf(pm, __shfl_xor(pm, 32));
      bool resc = !__all(pm <= mrow + 8.0f);
      float mu = resc ? fmaxf(mrow, pm) : mrow;
      float ps = 0.f;
#pragma unroll
      for (int r = 0; r < 16; r++) { float p = exp2f(s0[r] - mu); s0[r] = p; ps += p; }
#pragma unroll
      for (int r = 0; r < 16; r++) { float p = exp2f(s1[r] - mu); s1[r] = p; ps += p; }
      ps += __shfl_xor(ps, 32);
      if (resc) {
        float corr = exp2f(mrow - mu);
        lrow = lrow * corr + ps;
        mrow = mu;
#pragma unroll
        for (int r = 0; r < 16; r++) { o0[r] *= corr; o1[r] *= corr; }
      } else {
        lrow += ps;
      }

      // P^T B-fragments in-register: cvt_pk + permlane32_swap (T12)
      s16x8 pfr[4];
#pragma unroll
      for (int fb = 0; fb < 4; fb++) {
        const f32x16& tile = (fb < 2) ? s0 : s1;
        const int base = (fb & 1) * 8;
        unsigned X = cvtpk(tile[base + 0], tile[base + 1]);
        unsigned Y = cvtpk(tile[base + 2], tile[base + 3]);
        unsigned Z = cvtpk(tile[base + 4], tile[base + 5]);
        unsigned Wd = cvtpk(tile[base + 6], tile[base + 7]);
        pl32swap(X, Z);
        pl32swap(Y, Wd);
        u32x4 wq; wq.x = X; wq.y = Y; wq.z = Z; wq.w = Wd;
        pfr[fb] = __builtin_bit_cast(s16x8, wq);
      }

      // O^T += V^T * P
      __builtin_amdgcn_s_setprio(1);
#pragma unroll
      for (int ss = 0; ss < 4; ss++) {
        int sl = ((2 * ss + hi) ^ sxor) * 8;
        s16x8 va = *(const s16x8*)(Vc + ln32 * 64 + sl);
        o0 = __builtin_amdgcn_mfma_f32_32x32x16_bf16(va, pfr[ss], o0, 0, 0, 0);
        s16x8 vb = *(const s16x8*)(Vc + (32 + ln32) * 64 + sl);
        o1 = __builtin_amdgcn_mfma_f32_32x32x16_bf16(vb, pfr[ss], o1, 0, 0, 0);
      }
      __builtin_amdgcn_s_setprio(0);
    }

    __builtin_amdgcn_sched_barrier(0);
    asm volatile("s_waitcnt lgkmcnt(0)" ::: "memory");
    __builtin_amdgcn_s_barrier();
    cur ^= 1;
  }
#undef STAGEKV

  if (pidx < 0) {
    float linv = 1.0f / lrow;
    int orow = b * SEQ + qg;
    __hip_bfloat16* ob = attn + (size_t)orow * HID + h * HD;
#pragma unroll
    for (int rp = 0; rp < 16; rp += 2) {
      int d0 = (rp & 3) + 8 * (rp >> 2) + 4 * hi;
      *(unsigned*)(ob + d0)      = pk2(o0[rp] * linv, o0[rp + 1] * linv);
      *(unsigned*)(ob + 32 + d0) = pk2(o1[rp] * linv, o1[rp + 1] * linv);
    }
  } else {
    int tq = wv * 32 + ln32;
    __hip_bfloat16* pob = PO + ((size_t)pidx * 256 + tq) * 64;
#pragma unroll
    for (int rp = 0; rp < 16; rp += 2) {
      int d0 = (rp & 3) + 8 * (rp >> 2) + 4 * hi;
      *(unsigned*)(pob + d0)      = pk2(o0[rp], o0[rp + 1]);
      *(unsigned*)(pob + 32 + d0) = pk2(o1[rp], o1[rp + 1]);
    }
    if (hi == 0) {
      PM[pidx * 256 + tq] = mrow;
      PL[pidx * 256 + tq] = lrow;
    }
  }
}

// ---------------- combine partials ----------------
__global__ __launch_bounds__(256) void combine(const __hip_bfloat16* __restrict__ PO,
                                               const float* __restrict__ PM,
                                               const float* __restrict__ PL,
                                               __hip_bfloat16* __restrict__ attn) {
  int bi = blockIdx.x;
  int b, h, qtl, ns, pbase;
  if (bi < 360) {
    int lidx = bi / 6, j2 = bi % 6;
    qtl = QT6[j2]; ns = 2; pbase = lidx * 12 + j2 * 2;
    b = lidx / 30; h = lidx % 30;
  } else {
    int gi = bi - 360;
    int gidx = gi / 12, j2 = gi % 12;
    qtl = 4 + j2; ns = (qtl >> 2) + 1;
    pbase = 720 + gidx * 36 + PG12[j2];
    b = gidx >> 1; h = 30 + (gidx & 1);
  }
  int tq = threadIdx.x;
  float m = -3.0e38f;
  for (int s = 0; s < ns; s++) m = fmaxf(m, PM[(pbase + s) * 256 + tq]);
  float wsum = 0.f;
  float oacc[64];
#pragma unroll
  for (int d = 0; d < 64; d++) oacc[d] = 0.f;
  for (int s = 0; s < ns; s++) {
    float w = exp2f(PM[(pbase + s) * 256 + tq] - m);
    wsum += w * PL[(pbase + s) * 256 + tq];
    const s16x8* po = (const s16x8*)(PO + ((size_t)(pbase + s) * 256 + tq) * 64);
#pragma unroll
    for (int u = 0; u < 8; u++) {
      s16x8 v = po[u];
#pragma unroll
      for (int e = 0; e < 8; e++) {
        union { unsigned uu; float f; } cv;
        cv.uu = ((unsigned)(unsigned short)v[e]) << 16;
        oacc[u * 8 + e] += w * cv.f;
      }
    }
  }
  float inv = 1.0f / wsum;
  __hip_bfloat16* ob = attn + ((size_t)(b * SEQ + qtl * 256 + tq)) * HID + h * HD;
#pragma unroll
  for (int d = 0; d < 64; d += 2)
    *(unsigned*)(ob + d) = pk2(oacc[d] * inv, oacc[d + 1] * inv);
}

extern "C" void kernel_launch(void* const* d_in, const int* in_sizes, int n_in,
                              void* d_out, int out_size, void* d_ws, size_t ws_size,
                              hipStream_t stream) {
  (void)in_sizes; (void)n_in; (void)out_size; (void)ws_size;
  const float* hid = (const float*)d_in[0];
  const float* Wq  = (const float*)d_in[1];
  const float* Wk  = (const float*)d_in[2];
  const float* Wv  = (const float*)d_in[3];
  const float* Wo  = (const float*)d_in[4];
  const float* bo  = (const float*)d_in[5];

  char* ws = (char*)d_ws;
  size_t off = 0;
  __hip_bfloat16* hidB = (__hip_bfloat16*)(ws + off); off += (size_t)ROWS * HID * 2;
  __hip_bfloat16* WqB  = (__hip_bfloat16*)(ws + off); off += (size_t)HID * HID * 2;
  __hip_bfloat16* WkB  = (__hip_bfloat16*)(ws + off); off += (size_t)HID * HID * 2;
  __hip_bfloat16* WvB  = (__hip_bfloat16*)(ws + off); off += (size_t)HID * HID * 2;
  __hip_bfloat16* WoB  = (__hip_bfloat16*)(ws + off); off += (size_t)HID * HID * 2;
  __hip_bfloat16* Qr   = (__hip_bfloat16*)(ws + off); off += (size_t)ROWS * HID * 2;
  __hip_bfloat16* Kr   = (__hip_bfloat16*)(ws + off); off += (size_t)ROWS * HID * 2;
  __hip_bfloat16* vlin = (__hip_bfloat16*)(ws + off); off += (size_t)ROWS * HID * 2;
  __hip_bfloat16* PO   = (__hip_bfloat16*)(ws + off); off += (size_t)864 * 256 * 64 * 2;
  float* PM            = (float*)(ws + off);          off += (size_t)864 * 256 * 4;
  float* PL            = (float*)(ws + off);          off += (size_t)864 * 256 * 4;
  __hip_bfloat16* Vt   = hidB;       // alias: hidden bf16 dead after QKV GEMMs
  __hip_bfloat16* attn = vlin;       // alias: vlin dead after transpose_v

  castk<<<(ROWS * HID / 8 + 255) / 256, 256, 0, stream>>>(hid, hidB, ROWS * HID / 8);
  castw<<<dim3(HID * HID / 8 / 256, 4), 256, 0, stream>>>(Wq, Wk, Wv, Wo, WqB);

  dim3 gg(HID / 256, ROWS / 256);   // 8 x 32 = 256 blocks
  gemm256<1><<<gg, 512, 0, stream>>>(hidB, WqB, nullptr, (void*)Qr);
  gemm256<2><<<gg, 512, 0, stream>>>(hidB, WkB, nullptr, (void*)Kr);
  gemm256<0><<<gg, 512, 0, stream>>>(hidB, WvB, nullptr, (void*)vlin);

  transpose_v<<<BATCH * NH * (SEQ / 64), 256, 0, stream>>>(vlin, Vt);

  flash<<<1480, 512, 0, stream>>>(Qr, Kr, Vt, attn, PO, PM, PL);
  combine<<<408, 256, 0, stream>>>(PO, PM, PL, attn);

  gemm256<3><<<gg, 512, 0, stream>>>(attn, WoB, bo, d_out);
}

// Round 7
// 457.417 us; speedup vs baseline: 1.8367x; 1.2534x over previous
//
#include <hip/hip_runtime.h>
#include <hip/hip_bf16.h>
#include <stdint.h>

#define HID 2048
#define SEQ 4096
#define BATCH 2
#define NH 32
#define HD 64
#define ROWS (BATCH*SEQ)
#define LOCAL_H 30
#define LOG2E 1.4426950408889634f
#define NT 32              // K tiles of 64 in 2048

typedef __attribute__((ext_vector_type(4))) float f32x4;
typedef __attribute__((ext_vector_type(16))) float f32x16;
typedef __attribute__((ext_vector_type(8))) short s16x8;
typedef __attribute__((ext_vector_type(4))) unsigned int u32x4;

__device__ __forceinline__ void g2l16(const void* g, void* l) {
  __builtin_amdgcn_global_load_lds((__attribute__((address_space(1))) void*)(g),
                                   (__attribute__((address_space(3))) void*)(l), 16, 0, 0);
}

__device__ __forceinline__ unsigned pk2(float a, float b) {
  union { __hip_bfloat16 h; unsigned short u; } x, y;
  x.h = __float2bfloat16(a); y.h = __float2bfloat16(b);
  return ((unsigned)y.u << 16) | x.u;
}

__device__ __forceinline__ unsigned cvtpk(float lo, float hi) {
  unsigned d;
  asm("v_cvt_pk_bf16_f32 %0, %1, %2" : "=v"(d) : "v"(lo), "v"(hi));
  return d;
}

__device__ __forceinline__ void pl32swap(unsigned &a, unsigned &b) {
  asm volatile("v_permlane32_swap_b32 %0, %1" : "+v"(a), "+v"(b));
}

// segment decode tables (flash) and combine tables
__device__ const unsigned char Gq40[40] = {0,1,2,3, 4,4,5,5,6,6,7,7,
  8,8,8,9,9,9,10,10,10,11,11,11, 12,12,12,12,13,13,13,13,14,14,14,14,15,15,15,15};
__device__ const unsigned char Gs40[40] = {0,0,0,0, 0,1,0,1,0,1,0,1,
  0,1,2,0,1,2,0,1,2,0,1,2, 0,1,2,3,0,1,2,3,0,1,2,3,0,1,2,3};
__device__ const unsigned char PG16[16] = {0,0,0,0, 0,2,4,6, 8,11,14,17, 20,24,28,32};
__device__ const unsigned char Lq22[22] = {6,6,7,7,10,10,11,11,14,14,15,15, 0,1,2,3,4,5,8,9,12,13};
__device__ const unsigned char Ls22[22] = {0,1,0,1,0,1,0,1,0,1,0,1, 0,0,0,0,0,0,0,0,0,0};
__device__ const unsigned char QT6[6]   = {6,7,10,11,14,15};
__device__ const unsigned char PG12[12] = {0,2,4,6,8,11,14,17,20,24,28,32};

// ---------------- cast f32 -> bf16 ----------------
__global__ __launch_bounds__(256) void castk(const float* __restrict__ s,
                                             __hip_bfloat16* __restrict__ d, int n8) {
  int i = blockIdx.x * 256 + threadIdx.x;
  if (i >= n8) return;
  const f32x4* sp = (const f32x4*)(s) + (size_t)i * 2;
  f32x4 a = sp[0], b = sp[1];
  __hip_bfloat16 t[8];
#pragma unroll
  for (int j = 0; j < 4; j++) { t[j] = __float2bfloat16(a[j]); t[j+4] = __float2bfloat16(b[j]); }
  *(s16x8*)(d + (size_t)i * 8) = *(const s16x8*)t;
}

// cast 4 weights (dsts contiguous at dbase + y*HID*HID)
__global__ __launch_bounds__(256) void castw(const float* __restrict__ w0,
                                             const float* __restrict__ w1,
                                             const float* __restrict__ w2,
                                             const float* __restrict__ w3,
                                             __hip_bfloat16* __restrict__ dbase) {
  const float* s = (blockIdx.y == 0) ? w0 : (blockIdx.y == 1) ? w1 : (blockIdx.y == 2) ? w2 : w3;
  __hip_bfloat16* d = dbase + (size_t)blockIdx.y * HID * HID;
  int i = blockIdx.x * 256 + threadIdx.x;
  const f32x4* sp = (const f32x4*)(s) + (size_t)i * 2;
  f32x4 a = sp[0], b = sp[1];
  __hip_bfloat16 t[8];
#pragma unroll
  for (int j = 0; j < 4; j++) { t[j] = __float2bfloat16(a[j]); t[j+4] = __float2bfloat16(b[j]); }
  *(s16x8*)(d + (size_t)i * 8) = *(const s16x8*)t;
}

// ---------------- 256x256 NT GEMM, B-frags hoisted, fused epilogues ----------------
// OP 0: fused QKV (which = bx>>3: 0->Q RoPE+scale, 1->K RoPE, 2->V transposed to Vt)
// OP 1: O-projection, f32 out + bias
template<int OP>
__global__ __launch_bounds__(512, 2) void gemm256(const __hip_bfloat16* __restrict__ A,
                                                  const __hip_bfloat16* __restrict__ Wbase,
                                                  const float* __restrict__ bias,
                                                  __hip_bfloat16* __restrict__ Qr,
                                                  __hip_bfloat16* __restrict__ Kr,
                                                  __hip_bfloat16* __restrict__ Vt,
                                                  float* __restrict__ Oout) {
  __shared__ __hip_bfloat16 lds[2][4][128 * 64];   // [buf][A0,A1,B0,B1]
  const int tid = threadIdx.x;
  const int lane = tid & 63, wv = tid >> 6;
  const int wm = wv >> 2, wn = wv & 3;
  const int g = lane >> 4, ln = lane & 15;
  const int m0 = blockIdx.y * 256;

  int which, n0;
  const __hip_bfloat16* W;
  if constexpr (OP == 0) {
    which = blockIdx.x >> 3; n0 = (blockIdx.x & 7) * 256;
    W = Wbase + (size_t)which * HID * HID;
  } else {
    which = 3; n0 = blockIdx.x * 256; W = Wbase;
  }

  const int srow = tid >> 3, sslot = tid & 7;
  const int scolE = (sslot ^ (srow & 7)) * 8;
  const int srow2 = (512 + tid) >> 3;
  const int scolE2 = (sslot ^ (srow2 & 7)) * 8;

#define STAGE(srcbase, kt, region)                                              \
  {                                                                             \
    g2l16((srcbase) + (size_t)(srow) * HID + (kt) + scolE,                      \
          (void*)(&lds[0][0][0] + (region) * 8192 + wv * 512));                 \
    g2l16((srcbase) + (size_t)(srow2) * HID + (kt) + scolE2,                    \
          (void*)(&lds[0][0][0] + (region) * 8192 + 4096 + wv * 512));          \
  }

  f32x4 acc[8][4];
#pragma unroll
  for (int i = 0; i < 8; i++)
#pragma unroll
    for (int j = 0; j < 4; j++) acc[i][j] = (f32x4)0.f;

  // prologue: tile 0 into buf 0, order A0,B0,B1,A1
  STAGE(A + (size_t)m0 * HID,           0, 0);
  STAGE(W + (size_t)n0 * HID,           0, 2);
  STAGE(W + (size_t)(n0 + 128) * HID,   0, 3);
  STAGE(A + (size_t)(m0 + 128) * HID,   0, 1);

  for (int t = 0; t < NT; ++t) {
    const int buf = t & 1, nbuf = buf ^ 1;
    const int ktn = (t + 1) * 64;
    const bool pre = (t + 1 < NT);
    const __hip_bfloat16* Bh = &lds[buf][2 + (wn >> 1)][0];
    s16x8 bfv[4][2];

#pragma unroll
    for (int mi = 0; mi < 2; mi++) {
      if (pre) {
        if (mi == 0) { STAGE(A + (size_t)m0 * HID,         ktn, nbuf * 4 + 0) }  // A0'
        else         { STAGE(W + (size_t)(n0 + 128) * HID, ktn, nbuf * 4 + 3) }  // B1'
        if (mi == 0) { asm volatile("s_waitcnt vmcnt(4)" ::: "memory"); }
        else         { asm volatile("s_waitcnt vmcnt(6)" ::: "memory"); }
      } else if (mi == 0) {
        asm volatile("s_waitcnt vmcnt(0)" ::: "memory");
      }
      __builtin_amdgcn_sched_barrier(0);
      __builtin_amdgcn_s_barrier();
      __builtin_amdgcn_sched_barrier(0);

      const __hip_bfloat16* Ah = &lds[buf][mi][0];
      s16x8 af[4][2];
#pragma unroll
      for (int st = 0; st < 4; st++) {
        int row = wm * 64 + st * 16 + ln;
#pragma unroll
        for (int ks = 0; ks < 2; ks++)
          af[st][ks] = *(const s16x8*)(Ah + row * 64 + (((ks * 4 + g) ^ (row & 7)) * 8));
      }
      if (mi == 0) {   // hoist B-frags: read once per K-tile, keep live
#pragma unroll
        for (int nf = 0; nf < 4; nf++) {
          int row = (wn & 1) * 64 + nf * 16 + ln;
#pragma unroll
          for (int ks = 0; ks < 2; ks++)
            bfv[nf][ks] = *(const s16x8*)(Bh + row * 64 + (((ks * 4 + g) ^ (row & 7)) * 8));
        }
      }
#pragma unroll
      for (int ni = 0; ni < 2; ni++) {
        if (pre && ni == 1) {
          if (mi == 0) { STAGE(W + (size_t)n0 * HID,         ktn, nbuf * 4 + 2) }  // B0'
          else         { STAGE(A + (size_t)(m0 + 128) * HID, ktn, nbuf * 4 + 1) }  // A1'
        }
        __builtin_amdgcn_s_setprio(1);
#pragma unroll
        for (int st = 0; st < 4; st++)
#pragma unroll
          for (int st2 = 0; st2 < 2; st2++)
#pragma unroll
            for (int ks = 0; ks < 2; ks++)
              acc[mi * 4 + st][ni * 2 + st2] =
                __builtin_amdgcn_mfma_f32_16x16x32_bf16(af[st][ks], bfv[ni * 2 + st2][ks],
                                                        acc[mi * 4 + st][ni * 2 + st2], 0, 0, 0);
        __builtin_amdgcn_s_setprio(0);
      }
    }
  }
#undef STAGE

  const int n0c = n0 + (wn >> 1) * 128 + (wn & 1) * 64;
  if constexpr (OP == 1) {
#pragma unroll
    for (int am = 0; am < 8; am++) {
#pragma unroll
      for (int r = 0; r < 4; r++) {
        int grow = m0 + (am >> 2) * 128 + wm * 64 + (am & 3) * 16 + g * 4 + r;
        float* o = Oout + (size_t)grow * HID + n0c;
#pragma unroll
        for (int j = 0; j < 4; j++)
          o[j * 16 + ln] = acc[am][j][r] + bias[n0c + j * 16 + ln];
      }
    }
  } else if (which == 2) {
    // V: write transposed straight to Vt[(b*NH+h)*HD + d][l]
#pragma unroll
    for (int am = 0; am < 8; am++) {
      int growb = m0 + (am >> 2) * 128 + wm * 64 + (am & 3) * 16 + g * 4;
      int b = growb >> 12, l0 = growb & (SEQ - 1);
#pragma unroll
      for (int j = 0; j < 4; j++) {
        int c = n0c + j * 16 + ln;
        __hip_bfloat16* vp = Vt + ((size_t)(b * NH + (c >> 6)) * HD + (c & 63)) * SEQ + l0;
        *(unsigned*)(vp)     = pk2(acc[am][j][0], acc[am][j][1]);
        *(unsigned*)(vp + 2) = pk2(acc[am][j][2], acc[am][j][3]);
      }
    }
  } else {
    // Q or K: RoPE scatter to [b][h][l][d]
    __hip_bfloat16* outp = (which == 0) ? Qr : Kr;
    int h = n0c >> 6;
#pragma unroll
    for (int am = 0; am < 8; am++) {
      int growb = m0 + (am >> 2) * 128 + wm * 64 + (am & 3) * 16 + g * 4;
      int b = growb >> 12;
#pragma unroll
      for (int r = 0; r < 4; r++) {
        int l = (growb & (SEQ - 1)) + r;
        __hip_bfloat16* o = outp + ((size_t)(b * NH + h) * SEQ + l) * HD;
#pragma unroll
        for (int j = 0; j < 2; j++) {
          int d = j * 16 + ln;
          float x1 = acc[am][j][r], x2 = acc[am][j + 2][r];
          float ang = (float)l * exp2f((float)d * -0.41524101186091903f);
          float sn, cs;
          __sincosf(ang, &sn, &cs);
          float o1 = x1 * cs - x2 * sn;
          float o2 = x2 * cs + x1 * sn;
          if (which == 0) { o1 *= 0.125f * LOG2E; o2 *= 0.125f * LOG2E; }
          o[d]      = __float2bfloat16(o1);
          o[d + 32] = __float2bfloat16(o2);
        }
      }
    }
  }
}

// ---------------- flash attention: split-KV segments <=1024 keys (unchanged R5/R6) ----------------
__global__ __launch_bounds__(512, 4) void flash(const __hip_bfloat16* __restrict__ Q,
                                                const __hip_bfloat16* __restrict__ Kk,
                                                const __hip_bfloat16* __restrict__ Vt,
                                                __hip_bfloat16* __restrict__ attn,
                                                __hip_bfloat16* __restrict__ PO,
                                                float* __restrict__ PM,
                                                float* __restrict__ PL) {
  __shared__ __hip_bfloat16 Ks[2][64 * 64];
  __shared__ __hip_bfloat16 Vs[2][64 * 64];

  int bi = blockIdx.x;
  int b, h, qtl, seg, pidx;
  if (bi < 160) {                      // global heads (longest, dispatched first)
    int gidx = bi / 40, r = bi % 40;
    qtl = Gq40[r]; seg = Gs40[r];
    int nseg = (qtl >> 2) + 1;
    b = gidx >> 1; h = 30 + (gidx & 1);
    pidx = (nseg > 1) ? (720 + gidx * 36 + PG16[qtl] + seg) : -1;
  } else {
    int li = bi - 160;
    int lidx = li / 22, r = li % 22;
    qtl = Lq22[r]; seg = Ls22[r];
    b = lidx / 30; h = lidx % 30;
    pidx = (r < 12) ? (lidx * 12 + r) : -1;
  }
  const int bhid = b * NH + h;
  const int q0 = qtl * 256;
  int ks0t = 0;
  if (h < LOCAL_H) { int gq = qtl >> 2; ks0t = gq ? gq * 1024 - 512 : 0; }
  const int kstart = ks0t + seg * 1024;
  const int kend_t = q0 + 256;
  const int kend_s = (kend_t < kstart + 1024) ? kend_t : kstart + 1024;
  const int nch = (kend_s - kstart) >> 6;

  const int tid = threadIdx.x, lane = tid & 63, wv = tid >> 6;
  const int ln32 = lane & 31, hi = lane >> 5;
  const int qw0 = q0 + wv * 32;
  const int qg = qw0 + ln32;

  const __hip_bfloat16* qb = Q + ((size_t)bhid * SEQ + qg) * HD + hi * 8;
  s16x8 qf[4];
#pragma unroll
  for (int tt = 0; tt < 4; tt++) qf[tt] = *(const s16x8*)(qb + tt * 16);

  float mrow = -3.0e38f, lrow = 0.f;
  f32x16 o0 = (f32x16)0.f, o1 = (f32x16)0.f;

  const int srow = tid >> 3, sslot = tid & 7;
  const int scolE = (sslot ^ (srow & 7) ^ ((srow >> 1) & 4)) * 8;
  const int sxor = (ln32 & 7) ^ ((ln32 >> 1) & 4);

#define STAGEKV(bb, kc)                                                                   \
  {                                                                                       \
    g2l16(Kk + ((size_t)bhid * SEQ + (kc) + srow) * HD + scolE, (void*)(&Ks[bb][0] + wv * 512)); \
    g2l16(Vt + ((size_t)bhid * HD + srow) * SEQ + (kc) + scolE, (void*)(&Vs[bb][0] + wv * 512)); \
  }

  STAGEKV(0, kstart)

  int cur = 0;
  for (int ci = 0; ci < nch; ci++) {
    int kc = kstart + ci * 64;
    if (ci + 1 < nch) {
      STAGEKV(cur ^ 1, kc + 64)
      asm volatile("s_waitcnt vmcnt(2)" ::: "memory");
    } else {
      asm volatile("s_waitcnt vmcnt(0)" ::: "memory");
    }
    __builtin_amdgcn_s_barrier();
    __builtin_amdgcn_sched_barrier(0);

    if (kc <= qw0 + 31) {            // wave-uniform skip of fully-masked chunks
      const __hip_bfloat16* Kc = &Ks[cur][0];
      const __hip_bfloat16* Vc = &Vs[cur][0];

      f32x16 s0 = (f32x16)0.f, s1 = (f32x16)0.f;
      __builtin_amdgcn_s_setprio(1);
#pragma unroll
      for (int tt = 0; tt < 4; tt++) {
        int sl = ((2 * tt + hi) ^ sxor) * 8;
        s16x8 ka = *(const s16x8*)(Kc + ln32 * 64 + sl);
        s0 = __builtin_amdgcn_mfma_f32_32x32x16_bf16(ka, qf[tt], s0, 0, 0, 0);
        s16x8 kb = *(const s16x8*)(Kc + (32 + ln32) * 64 + sl);
        s1 = __builtin_amdgcn_mfma_f32_32x32x16_bf16(kb, qf[tt], s1, 0, 0, 0);
      }
      __builtin_amdgcn_s_setprio(0);

      if (kc + 63 > qw0) {           // diagonal region: mask kv > q
#pragma unroll
        for (int r = 0; r < 16; r++) {
          int kv0 = kc + (r & 3) + 8 * (r >> 2) + 4 * hi;
          if (kv0 > qg) s0[r] = -1.0e30f;
          if (kv0 + 32 > qg) s1[r] = -1.0e30f;
        }
      }

      // per-lane online softmax (log2 domain), defer-max (T13, thr=8)
      float pm = fmaxf(s0[0], s1[0]);
#pragma unroll
      for (int r = 1; r < 16; r++) pm = fmaxf(pm, fmaxf(s0[r], s1[r]));
      pm = fmaxf(pm, __shfl_xor(pm, 32));
      bool resc = !__all(pm <= mrow + 8.0f);
      float mu = resc ? fmaxf(mrow, pm) : mrow;
      float ps = 0.f;
#pragma unroll
      for (int r = 0; r < 16; r++) { float p = exp2f(s0[r] - mu); s0[r] = p; ps += p; }
#pragma unroll
      for (int r = 0; r < 16; r++) { float p = exp2f(s1[r] - mu); s1[r] = p; ps += p; }
      ps += __shfl_xor(ps, 32);
      if (resc) {
        float corr = exp2f(mrow - mu);
        lrow = lrow * corr + ps;
        mrow = mu;
#pragma unroll
        for (int r = 0; r < 16; r++) { o0[r] *= corr; o1[r] *= corr; }
      } else {
        lrow += ps;
      }

      // P^T B-fragments in-register: cvt_pk + permlane32_swap (T12)
      s16x8 pfr[4];
#pragma unroll
      for (int fb = 0; fb < 4; fb++) {
        const f32x16& tile = (fb < 2) ? s0 : s1;
        const int base = (fb & 1) * 8;
        unsigned X = cvtpk(tile[base + 0], tile[base + 1]);
        unsigned Y = cvtpk(tile[base + 2], tile[base + 3]);
        unsigned Z = cvtpk(tile[base + 4], tile[base + 5]);
        unsigned Wd = cvtpk(tile[base + 6], tile[base + 7]);
        pl32swap(X, Z);
        pl32swap(Y, Wd);
        u32x4 wq; wq.x = X; wq.y = Y; wq.z = Z; wq.w = Wd;
        pfr[fb] = __builtin_bit_cast(s16x8, wq);
      }

      // O^T += V^T * P
      __builtin_amdgcn_s_setprio(1);
#pragma unroll
      for (int ss = 0; ss < 4; ss++) {
        int sl = ((2 * ss + hi) ^ sxor) * 8;
        s16x8 va = *(const s16x8*)(Vc + ln32 * 64 + sl);
        o0 = __builtin_amdgcn_mfma_f32_32x32x16_bf16(va, pfr[ss], o0, 0, 0, 0);
        s16x8 vb = *(const s16x8*)(Vc + (32 + ln32) * 64 + sl);
        o1 = __builtin_amdgcn_mfma_f32_32x32x16_bf16(vb, pfr[ss], o1, 0, 0, 0);
      }
      __builtin_amdgcn_s_setprio(0);
    }

    __builtin_amdgcn_sched_barrier(0);
    asm volatile("s_waitcnt lgkmcnt(0)" ::: "memory");
    __builtin_amdgcn_s_barrier();
    cur ^= 1;
  }
#undef STAGEKV

  if (pidx < 0) {
    float linv = 1.0f / lrow;
    int orow = b * SEQ + qg;
    __hip_bfloat16* ob = attn + (size_t)orow * HID + h * HD;
#pragma unroll
    for (int rp = 0; rp < 16; rp += 2) {
      int d0 = (rp & 3) + 8 * (rp >> 2) + 4 * hi;
      *(unsigned*)(ob + d0)      = pk2(o0[rp] * linv, o0[rp + 1] * linv);
      *(unsigned*)(ob + 32 + d0) = pk2(o1[rp] * linv, o1[rp + 1] * linv);
    }
  } else {
    int tq = wv * 32 + ln32;
    __hip_bfloat16* pob = PO + ((size_t)pidx * 256 + tq) * 64;
#pragma unroll
    for (int rp = 0; rp < 16; rp += 2) {
      int d0 = (rp & 3) + 8 * (rp >> 2) + 4 * hi;
      *(unsigned*)(pob + d0)      = pk2(o0[rp], o0[rp + 1]);
      *(unsigned*)(pob + 32 + d0) = pk2(o1[rp], o1[rp + 1]);
    }
    if (hi == 0) {
      PM[pidx * 256 + tq] = mrow;
      PL[pidx * 256 + tq] = lrow;
    }
  }
}

// ---------------- combine partials ----------------
__global__ __launch_bounds__(256) void combine(const __hip_bfloat16* __restrict__ PO,
                                               const float* __restrict__ PM,
                                               const float* __restrict__ PL,
                                               __hip_bfloat16* __restrict__ attn) {
  int bi = blockIdx.x;
  int b, h, qtl, ns, pbase;
  if (bi < 360) {
    int lidx = bi / 6, j2 = bi % 6;
    qtl = QT6[j2]; ns = 2; pbase = lidx * 12 + j2 * 2;
    b = lidx / 30; h = lidx % 30;
  } else {
    int gi = bi - 360;
    int gidx = gi / 12, j2 = gi % 12;
    qtl = 4 + j2; ns = (qtl >> 2) + 1;
    pbase = 720 + gidx * 36 + PG12[j2];
    b = gidx >> 1; h = 30 + (gidx & 1);
  }
  int tq = threadIdx.x;
  float m = -3.0e38f;
  for (int s = 0; s < ns; s++) m = fmaxf(m, PM[(pbase + s) * 256 + tq]);
  float wsum = 0.f;
  float oacc[64];
#pragma unroll
  for (int d = 0; d < 64; d++) oacc[d] = 0.f;
  for (int s = 0; s < ns; s++) {
    float w = exp2f(PM[(pbase + s) * 256 + tq] - m);
    wsum += w * PL[(pbase + s) * 256 + tq];
    const s16x8* po = (const s16x8*)(PO + ((size_t)(pbase + s) * 256 + tq) * 64);
#pragma unroll
    for (int u = 0; u < 8; u++) {
      s16x8 v = po[u];
#pragma unroll
      for (int e = 0; e < 8; e++) {
        union { unsigned uu; float f; } cv;
        cv.uu = ((unsigned)(unsigned short)v[e]) << 16;
        oacc[u * 8 + e] += w * cv.f;
      }
    }
  }
  float inv = 1.0f / wsum;
  __hip_bfloat16* ob = attn + ((size_t)(b * SEQ + qtl * 256 + tq)) * HID + h * HD;
#pragma unroll
  for (int d = 0; d < 64; d += 2)
    *(unsigned*)(ob + d) = pk2(oacc[d] * inv, oacc[d + 1] * inv);
}

extern "C" void kernel_launch(void* const* d_in, const int* in_sizes, int n_in,
                              void* d_out, int out_size, void* d_ws, size_t ws_size,
                              hipStream_t stream) {
  (void)in_sizes; (void)n_in; (void)out_size; (void)ws_size;
  const float* hid = (const float*)d_in[0];
  const float* Wq  = (const float*)d_in[1];
  const float* Wk  = (const float*)d_in[2];
  const float* Wv  = (const float*)d_in[3];
  const float* Wo  = (const float*)d_in[4];
  const float* bo  = (const float*)d_in[5];

  char* ws = (char*)d_ws;
  size_t off = 0;
  __hip_bfloat16* hidB = (__hip_bfloat16*)(ws + off); off += (size_t)ROWS * HID * 2;
  __hip_bfloat16* WqB  = (__hip_bfloat16*)(ws + off); off += (size_t)HID * HID * 2 * 4;  // Wq,Wk,Wv,Wo contiguous
  __hip_bfloat16* WoB  = WqB + (size_t)3 * HID * HID;
  __hip_bfloat16* Qr   = (__hip_bfloat16*)(ws + off); off += (size_t)ROWS * HID * 2;
  __hip_bfloat16* Kr   = (__hip_bfloat16*)(ws + off); off += (size_t)ROWS * HID * 2;
  __hip_bfloat16* Vt   = (__hip_bfloat16*)(ws + off); off += (size_t)ROWS * HID * 2;
  __hip_bfloat16* PO   = (__hip_bfloat16*)(ws + off); off += (size_t)864 * 256 * 64 * 2;
  float* PM            = (float*)(ws + off);          off += (size_t)864 * 256 * 4;
  float* PL            = (float*)(ws + off);          off += (size_t)864 * 256 * 4;
  __hip_bfloat16* attn = hidB;     // alias: hidB dead after the QKV GEMM

  castk<<<(ROWS * HID / 8 + 255) / 256, 256, 0, stream>>>(hid, hidB, ROWS * HID / 8);
  castw<<<dim3(HID * HID / 8 / 256, 4), 256, 0, stream>>>(Wq, Wk, Wv, Wo, WqB);

  // fused Q,K,V projection: 24 x-blocks (3 weights x 8 n-tiles) x 32 m-tiles
  gemm256<0><<<dim3(24, 32), 512, 0, stream>>>(hidB, WqB, nullptr, Qr, Kr, Vt, nullptr);

  flash<<<1480, 512, 0, stream>>>(Qr, Kr, Vt, attn, PO, PM, PL);
  combine<<<408, 256, 0, stream>>>(PO, PM, PL, attn);

  gemm256<1><<<dim3(8, 32), 512, 0, stream>>>(attn, WoB, bo, nullptr, nullptr, nullptr, (float*)d_out);
}